// Round 11
// baseline (139.754 us; speedup 1.0000x reference)
//
#include <hip/hip_runtime.h>
#include <hip/hip_bf16.h>

#define FIN 128
#define FOUT 64
#define TILE_ROWS 64       // rows per gemm block = 4 waves x 16

#define EPB 8192           // edges per scatter chunk (98 blocks, runs ~5.2)
#define NPB 32             // nodes per bucket (d >> 5)
#define NBUK_MAX 1600
#define CAP 768            // records per bucket region (mean 512, +11 sigma)

// Workspace layout (bytes), ws >= 268 MB:
//   [0, 6,400,000)         support : N*64 bf16
//   OFF_CUR   +6,400       cur     : NBUK int (bucket fill counters)
//   OFF_OVFC  +64          ovfc    : 1 int (overflow count)
//   OFF_TMP   +9,830,400   tmp     : NBUK_MAX*CAP int2 regions {src|dloc<<16, ev}
//   OFF_OVF   +12,800,000  ovf     : E int4 {recx, recy, bucket, pad}
#define OFF_CUR   6400000
#define OFF_OVFC  6406400
#define OFF_TMP   6406464
#define OFF_OVF   16236864

typedef short bf16x8 __attribute__((ext_vector_type(8)));
typedef float f32x4  __attribute__((ext_vector_type(4)));

__device__ inline ushort f32_to_bf16_rne(float f) {
    unsigned u = __float_as_uint(f);
    u += 0x7FFFu + ((u >> 16) & 1u);
    return (ushort)(u >> 16);
}
__device__ inline float bf16_to_f32(ushort h) {
    return __uint_as_float((unsigned)h << 16);
}

// ---------------------------------------------------------------------------
// Fused, independent branches (no fences, no intra-kernel ordering):
//   blocks [0,SBP):      scatter chunk -> fixed-CAP 32-node-bucket regions.
//                        FIRST in grid: launches at t=0, overlaps GEMM (the
//                        782 gemm blocks keep the machine full; R5's lesson
//                        was that scatter-last + EPB 8192 = idle tail).
//   blocks [SBP,..):     MFMA gemm (W staged to LDS bf16, transposed+swz).
// Scatter: LDS hist of the chunk -> ONE returning global atomicAdd per
// present bucket (range reservation) -> place via LDS cursors. EPB=8192
// gives ~5.2-record runs per (chunk,bucket) -> write-combined tmp stores
// (R5 measured: WRITE_SIZE 15.3MB vs 51MB at EPB=2048).
// rec = {src | (d&31)<<16, ev_bits}   (src < 65536: N = 50000 ok)
// NOTE (R8 lesson): never use fp LDS atomics on gfx950 (308us RMW stall).
// NOTE (R9 lesson): TILE_ROWS=128 starves GEMM wave count; keep 64.
// ---------------------------------------------------------------------------
union __align__(16) K1Sh {
    ushort wt[FOUT * FIN];                            // 16 KB (gemm)
    struct { int h[NBUK_MAX]; int c[NBUK_MAX]; } sc;  // 12.8 KB (scatter)
};

__global__ __launch_bounds__(256) void gemm_scatter_kernel(
    const float* __restrict__ x, const float* __restrict__ t,
    const float* __restrict__ W, ushort* __restrict__ support, int N,
    const int* __restrict__ src, const int* __restrict__ dst,
    const float* __restrict__ ev, int* __restrict__ cur,
    int2* __restrict__ tmp, int* __restrict__ ovfc, int4* __restrict__ ovf,
    int E, int SBP, int NBUK, int GB)
{
    __shared__ K1Sh sh;
    const int tid = threadIdx.x;

    if (blockIdx.x < (unsigned)SBP) {
        // ---- scatter branch ----
        const int chunk = blockIdx.x;
        const int e0    = chunk * EPB;

        for (int i = tid; i < NBUK; i += 256) sh.sc.h[i] = 0;
        __syncthreads();

        // pass 1: local bucket counts
        for (int i = tid; i < EPB; i += 256) {
            int e = e0 + i;
            if (e < E) atomicAdd(&sh.sc.h[dst[e] >> 5], 1);
        }
        __syncthreads();

        // pass 2: reserve contiguous slices of bucket regions
        for (int j = tid; j < NBUK; j += 256) {
            int hj = sh.sc.h[j];
            if (hj) sh.sc.c[j] = atomicAdd(&cur[j], hj);
        }
        __syncthreads();

        // pass 3: place (dst re-read is L2-hot); same-bucket records land in
        // contiguous slots -> write-combined lines
        for (int i = tid; i < EPB; i += 256) {
            int e = e0 + i;
            if (e < E) {
                int d = dst[e];
                int j = d >> 5;
                int s = atomicAdd(&sh.sc.c[j], 1);
                int2 rec = make_int2(src[e] | ((d & (NPB - 1)) << 16),
                                     __float_as_int(ev[e]));
                if (s < CAP) {
                    tmp[(size_t)j * CAP + s] = rec;
                } else {                 // never at this size; kept correct
                    int o = atomicAdd(ovfc, 1);
                    if (o < E) ovf[o] = make_int4(rec.x, rec.y, j, 0);
                }
            }
        }
        return;
    }

    // ---- MFMA gemm branch ----
    const int gb   = blockIdx.x - SBP;
    const int lane = tid & 63;
    const int w    = tid >> 6;          // wave 0..3
    const int ln   = lane & 15;
    const int q    = lane >> 4;         // quad 0..3
    const int rowb = gb * TILE_ROWS + w * 16;
    const int arow = rowb + ln;

    // Stage W -> LDS bf16, transposed WT[n][k]; 16B slot XOR-swizzled by n&7.
    // Vectorized: 8 x float4 loads per thread.
    #pragma unroll
    for (int it = 0; it < 8; ++it) {
        int eidx = (tid + it * 256) * 4;        // element index; 4 consecutive n
        float4 wv = *(const float4*)&W[eidx];
        int k  = eidx >> 6;                     // 0..127
        int n0 = eidx & 63;                     // 0,4,..,60
        sh.wt[(n0 + 0) * FIN + (k ^ (((n0 + 0) & 7) << 3))] = f32_to_bf16_rne(wv.x);
        sh.wt[(n0 + 1) * FIN + (k ^ (((n0 + 1) & 7) << 3))] = f32_to_bf16_rne(wv.y);
        sh.wt[(n0 + 2) * FIN + (k ^ (((n0 + 2) & 7) << 3))] = f32_to_bf16_rne(wv.z);
        sh.wt[(n0 + 3) * FIN + (k ^ (((n0 + 3) & 7) << 3))] = f32_to_bf16_rne(wv.w);
    }
    __syncthreads();

    f32x4 acc[4];
    #pragma unroll
    for (int nt = 0; nt < 4; ++nt)
        #pragma unroll
        for (int r = 0; r < 4; ++r) acc[nt][r] = 0.f;

    const bool aok = (arow < N);
    const float* xrow = &x[(size_t)arow * FIN];

    #pragma unroll
    for (int kc = 0; kc < 4; ++kc) {
        float xs[8];
        #pragma unroll
        for (int j = 0; j < 8; ++j) xs[j] = 0.f;
        if (aok) {
            float4 x0 = *(const float4*)&xrow[kc * 32 + q * 8];
            float4 x1 = *(const float4*)&xrow[kc * 32 + q * 8 + 4];
            xs[0] = x0.x; xs[1] = x0.y; xs[2] = x0.z; xs[3] = x0.w;
            xs[4] = x1.x; xs[5] = x1.y; xs[6] = x1.z; xs[7] = x1.w;
        }
        bf16x8 a;
        #pragma unroll
        for (int j = 0; j < 8; ++j) a[j] = (short)f32_to_bf16_rne(xs[j]);

        const int k0 = kc * 32 + q * 8;
        #pragma unroll
        for (int nt = 0; nt < 4; ++nt) {
            bf16x8 b = *(const bf16x8*)
                &sh.wt[(nt * 16 + ln) * FIN + (k0 ^ ((ln & 7) << 3))];
            acc[nt] = __builtin_amdgcn_mfma_f32_16x16x32_bf16(a, b, acc[nt], 0, 0, 0);
        }
    }

    // epilogue: D[m=q*4+reg][n=ln]; scale by t[row]; store bf16
    #pragma unroll
    for (int reg = 0; reg < 4; ++reg) {
        int r = rowb + q * 4 + reg;
        if (r < N) {
            float tv = t[r];
            #pragma unroll
            for (int nt = 0; nt < 4; ++nt)
                support[(size_t)r * FOUT + nt * 16 + ln] =
                    f32_to_bf16_rne(acc[nt][reg] * tv);
        }
    }
}

// ---------------------------------------------------------------------------
// bucket_gather: one block per 32-node bucket (1563 blocks). Sort
// (raw[] stage + count -> wave-0 shfl scan -> reorder), then walk v3:
// each 16-lane group owns 2 WHOLE nodes (no cross-group reduce, no
// divergent store): group accumulates the node's full 64-feature row
// (4 floats/lane), records 4-deep unrolled (16 gathers in flight/wave),
// then 16 lanes store float4 = 256B contiguous. Zero-count nodes fall
// out naturally (empty loop -> bias row). No float atomics normally.
// ---------------------------------------------------------------------------
__global__ __launch_bounds__(256) void bucket_gather_kernel(
    const int* __restrict__ curg, const int2* __restrict__ tmp,
    const ushort* __restrict__ support, const float* __restrict__ bias,
    float* __restrict__ out, const int* __restrict__ ovfc,
    const int4* __restrict__ ovf, int E, int N, int NBUK)
{
    __shared__ int2 raw[CAP];           // 6 KB
    __shared__ int2 sorted[CAP];        // 6 KB
    __shared__ int  cnt[NPB];
    __shared__ int  starts[NPB + 1];
    __shared__ int  cur[NPB];
    __shared__ int  novs;

    const int tid   = threadIdx.x;
    const int w     = tid >> 6;
    const int lane  = tid & 63;
    const int B     = blockIdx.x;
    const int node0 = B * NPB;

    const int base   = B * CAP;
    const int tot    = curg[B];
    const int placed = (tot < CAP) ? tot : CAP;

    if (tid < NPB) cnt[tid] = 0;
    __syncthreads();

    // single global read of the region: stage + count
    for (int i = tid; i < placed; i += 256) {
        int2 r = tmp[base + i];
        raw[i] = r;
        atomicAdd(&cnt[(r.x >> 16) & (NPB - 1)], 1);
    }
    __syncthreads();

    // wave-0 shfl scan over 32 counters
    if (tid < 64) {
        int v   = (tid < NPB) ? cnt[tid] : 0;
        int val = v;
        #pragma unroll
        for (int d = 1; d < NPB; d <<= 1) {
            int n = __shfl_up(val, d);
            if (tid >= d) val += n;
        }
        if (tid < NPB) {
            starts[tid] = val - v;
            cur[tid]    = val - v;
        }
        if (tid == 0) starts[NPB] = placed;
    }
    __syncthreads();

    // reorder LDS -> LDS
    for (int i = tid; i < placed; i += 256) {
        int2 r  = raw[i];
        int pos = atomicAdd(&cur[(r.x >> 16) & (NPB - 1)], 1);
        sorted[pos] = r;
    }
    __syncthreads();

    // ---- walk v3: group g of wave w owns nodes w*8 + g*2 + {0,1} ----
    const int fl = lane & 15;           // feature block 0..15 (4 feats each)
    const int g  = lane >> 4;           // group 0..3
    const float4 bv4 = *(const float4*)&bias[fl * 4];

    #pragma unroll
    for (int sub = 0; sub < 2; ++sub) {
        const int nl = w * 8 + g * 2 + sub;   // node-local 0..31
        const int rb = starts[nl];
        const int re = starts[nl + 1];

        float a0 = 0.f, a1 = 0.f, a2 = 0.f, a3 = 0.f;
        int i = rb;
        for (; i + 4 <= re; i += 4) {          // 4 records in flight
            int2 r0 = sorted[i],     r1 = sorted[i + 1];
            int2 r2 = sorted[i + 2], r3 = sorted[i + 3];
            uint2 u0 = *(const uint2*)&support[(size_t)(r0.x & 0xFFFF) * FOUT + fl * 4];
            uint2 u1 = *(const uint2*)&support[(size_t)(r1.x & 0xFFFF) * FOUT + fl * 4];
            uint2 u2 = *(const uint2*)&support[(size_t)(r2.x & 0xFFFF) * FOUT + fl * 4];
            uint2 u3 = *(const uint2*)&support[(size_t)(r3.x & 0xFFFF) * FOUT + fl * 4];
            float w0 = __int_as_float(r0.y), w1 = __int_as_float(r1.y);
            float w2 = __int_as_float(r2.y), w3 = __int_as_float(r3.y);
            a0 += bf16_to_f32((ushort)(u0.x & 0xFFFFu)) * w0;
            a1 += bf16_to_f32((ushort)(u0.x >> 16)) * w0;
            a2 += bf16_to_f32((ushort)(u0.y & 0xFFFFu)) * w0;
            a3 += bf16_to_f32((ushort)(u0.y >> 16)) * w0;
            a0 += bf16_to_f32((ushort)(u1.x & 0xFFFFu)) * w1;
            a1 += bf16_to_f32((ushort)(u1.x >> 16)) * w1;
            a2 += bf16_to_f32((ushort)(u1.y & 0xFFFFu)) * w1;
            a3 += bf16_to_f32((ushort)(u1.y >> 16)) * w1;
            a0 += bf16_to_f32((ushort)(u2.x & 0xFFFFu)) * w2;
            a1 += bf16_to_f32((ushort)(u2.x >> 16)) * w2;
            a2 += bf16_to_f32((ushort)(u2.y & 0xFFFFu)) * w2;
            a3 += bf16_to_f32((ushort)(u2.y >> 16)) * w2;
            a0 += bf16_to_f32((ushort)(u3.x & 0xFFFFu)) * w3;
            a1 += bf16_to_f32((ushort)(u3.x >> 16)) * w3;
            a2 += bf16_to_f32((ushort)(u3.y & 0xFFFFu)) * w3;
            a3 += bf16_to_f32((ushort)(u3.y >> 16)) * w3;
        }
        for (; i < re; ++i) {
            int2 r = sorted[i];
            uint2 u = *(const uint2*)&support[(size_t)(r.x & 0xFFFF) * FOUT + fl * 4];
            float wg = __int_as_float(r.y);
            a0 += bf16_to_f32((ushort)(u.x & 0xFFFFu)) * wg;
            a1 += bf16_to_f32((ushort)(u.x >> 16)) * wg;
            a2 += bf16_to_f32((ushort)(u.y & 0xFFFFu)) * wg;
            a3 += bf16_to_f32((ushort)(u.y >> 16)) * wg;
        }
        const int node = node0 + nl;
        if (node < N) {
            float4 o;
            o.x = a0 + bv4.x; o.y = a1 + bv4.y;
            o.z = a2 + bv4.z; o.w = a3 + bv4.w;
            *(float4*)&out[(size_t)node * FOUT + fl * 4] = o;
        }
    }

    // overflow tail: never taken at this size; kept for correctness.
    __syncthreads();
    if (tid == 0) novs = *ovfc;
    __syncthreads();
    int nov = novs;
    if (nov > 0) {
        if (nov > E) nov = E;
        __threadfence();
        for (int k = w; k < nov; k += 4) {
            int4 r = ovf[k];
            if (r.z == B) {
                int node = node0 + ((r.x >> 16) & (NPB - 1));
                if (node < N) {
                    float v = bf16_to_f32(
                        support[(size_t)(r.x & 0xFFFF) * FOUT + lane]);
                    atomicAdd(&out[(size_t)node * FOUT + lane],
                              v * __int_as_float(r.y));
                }
            }
        }
    }
}

extern "C" void kernel_launch(void* const* d_in, const int* in_sizes, int n_in,
                              void* d_out, int out_size, void* d_ws, size_t ws_size,
                              hipStream_t stream) {
    const float* x    = (const float*)d_in[0];
    const float* t    = (const float*)d_in[1];
    const int*   src  = (const int*)d_in[2];
    const int*   dst  = (const int*)d_in[3];
    const float* ev   = (const float*)d_in[4];
    const float* W    = (const float*)d_in[5];
    const float* bias = (const float*)d_in[6];
    float* out = (float*)d_out;

    const int N = in_sizes[1];   // 50000
    const int E = in_sizes[2];   // 800000

    char*   ws      = (char*)d_ws;
    ushort* support = (ushort*)ws;
    int*    cur     = (int*)(ws + OFF_CUR);
    int*    ovfc    = (int*)(ws + OFF_OVFC);
    int2*   tmp     = (int2*)(ws + OFF_TMP);
    int4*   ovf     = (int4*)(ws + OFF_OVF);

    const int GB   = (N + TILE_ROWS - 1) / TILE_ROWS;       // 782
    const int SBP  = (E + EPB - 1) / EPB;                   // 98
    const int NBUK = (N + NPB - 1) / NPB;                   // 1563

    // zero bucket cursors + overflow count (6.5 KB, graph-capturable)
    hipMemsetAsync(ws + OFF_CUR, 0, OFF_TMP - OFF_CUR, stream);

    // 1) fused independent branches: scatter (first, overlaps) || MFMA gemm
    gemm_scatter_kernel<<<SBP + GB, 256, 0, stream>>>(
        x, t, W, support, N, src, dst, ev, cur, tmp, ovfc, ovf,
        E, SBP, NBUK, GB);

    // 2) per-bucket sort + group-per-node walk -> out (+bias)
    bucket_gather_kernel<<<NBUK, 256, 0, stream>>>(
        cur, tmp, support, bias, out, ovfc, ovf, E, N, NBUK);
}

// Round 12
// 126.762 us; speedup vs baseline: 1.1025x; 1.1025x over previous
//
#include <hip/hip_runtime.h>
#include <hip/hip_bf16.h>

#define FIN 128
#define FOUT 64
#define TILE_ROWS 256      // rows per gemm block = 16 waves x 16

#define EPB 8192           // edges per scatter chunk (98 blocks x 16 waves)
#define NPB 32             // nodes per bucket (d >> 5)
#define NBUK_MAX 1600
#define CAP 768            // records per bucket region (mean 512, +11 sigma)

// Workspace layout (bytes), ws >= 268 MB:
//   [0, 6,400,000)         support : N*64 bf16
//   OFF_CUR   +6,400       cur     : NBUK int (bucket fill counters)
//   OFF_OVFC  +64          ovfc    : 1 int (overflow count)
//   OFF_TMP   +9,830,400   tmp     : NBUK_MAX*CAP int2 regions {src|dloc<<16, ev}
//   OFF_OVF   +12,800,000  ovf     : E int4 {recx, recy, bucket, pad}
#define OFF_CUR   6400000
#define OFF_OVFC  6406400
#define OFF_TMP   6406464
#define OFF_OVF   16236864

typedef short bf16x8 __attribute__((ext_vector_type(8)));
typedef float f32x4  __attribute__((ext_vector_type(4)));

__device__ inline ushort f32_to_bf16_rne(float f) {
    unsigned u = __float_as_uint(f);
    u += 0x7FFFu + ((u >> 16) & 1u);
    return (ushort)(u >> 16);
}
__device__ inline float bf16_to_f32(ushort h) {
    return __uint_as_float((unsigned)h << 16);
}

// ---------------------------------------------------------------------------
// Fused, independent branches, 1024-thread blocks (no fences):
//   blocks [0,GB):       MFMA gemm, 256-row tiles (16 waves x 16 rows; W
//                        staged once per block -> 4x less staging than R10)
//   blocks [GB,GB+SBP):  scatter chunk EPB=8192 with 16 waves/block:
//                        per-thread work == R10 (8 edges/pass), total scatter
//                        waves 1568 == R10's parallelism, AND ~5.2-record
//                        runs -> write-combined tmp stores (R11 measured
//                        WRITE 21MB vs ~51MB at EPB 2048 / 256 thr).
// rec = {src | (d&31)<<16, ev_bits}   (src < 65536: N = 50000 ok)
// NOTE (R8): never use fp LDS atomics on gfx950 (308us RMW stall).
// NOTE (R9): few-block few-wave configs starve the machine; keep >=4 waves/SIMD.
// NOTE (R11): EPB 8192 at 256 thr/block = only 392 scatter waves -> 13us tail.
// ---------------------------------------------------------------------------
union __align__(16) K1Sh {
    ushort wt[FOUT * FIN];                            // 16 KB (gemm)
    struct { int h[NBUK_MAX]; int c[NBUK_MAX]; } sc;  // 12.8 KB (scatter)
};

__global__ __launch_bounds__(1024) void gemm_scatter_kernel(
    const float* __restrict__ x, const float* __restrict__ t,
    const float* __restrict__ W, ushort* __restrict__ support, int N,
    const int* __restrict__ src, const int* __restrict__ dst,
    const float* __restrict__ ev, int* __restrict__ cur,
    int2* __restrict__ tmp, int* __restrict__ ovfc, int4* __restrict__ ovf,
    int E, int SBP, int NBUK, int GB)
{
    __shared__ K1Sh sh;
    const int tid = threadIdx.x;

    if (blockIdx.x >= (unsigned)GB) {
        // ---- scatter branch: 16 waves, EPB 8192 ----
        const int chunk = blockIdx.x - GB;
        const int e0    = chunk * EPB;

        for (int i = tid; i < NBUK; i += 1024) sh.sc.h[i] = 0;
        __syncthreads();

        // pass 1: local bucket counts (8 edges/thread)
        for (int i = tid; i < EPB; i += 1024) {
            int e = e0 + i;
            if (e < E) atomicAdd(&sh.sc.h[dst[e] >> 5], 1);
        }
        __syncthreads();

        // pass 2: reserve contiguous slices of bucket regions
        for (int j = tid; j < NBUK; j += 1024) {
            int hj = sh.sc.h[j];
            if (hj) sh.sc.c[j] = atomicAdd(&cur[j], hj);
        }
        __syncthreads();

        // pass 3: place (dst re-read is L2-hot); ~5.2-record runs per bucket
        // land contiguously -> write-combined lines
        for (int i = tid; i < EPB; i += 1024) {
            int e = e0 + i;
            if (e < E) {
                int d = dst[e];
                int j = d >> 5;
                int s = atomicAdd(&sh.sc.c[j], 1);
                int2 rec = make_int2(src[e] | ((d & (NPB - 1)) << 16),
                                     __float_as_int(ev[e]));
                if (s < CAP) {
                    tmp[(size_t)j * CAP + s] = rec;
                } else {                 // never at this size; kept correct
                    int o = atomicAdd(ovfc, 1);
                    if (o < E) ovf[o] = make_int4(rec.x, rec.y, j, 0);
                }
            }
        }
        return;
    }

    // ---- MFMA gemm branch: 256-row tile, 16 waves x 16 rows ----
    const int gb   = blockIdx.x;
    const int lane = tid & 63;
    const int w    = tid >> 6;          // wave 0..15
    const int ln   = lane & 15;
    const int q    = lane >> 4;         // quad 0..3
    const int rowb = gb * TILE_ROWS + w * 16;
    const int arow = rowb + ln;

    // Stage W -> LDS bf16, transposed WT[n][k]; 16B slot XOR-swizzled by n&7.
    // Vectorized: 2 x float4 loads per thread (1024 thr x 2 x 4 = 8192 elems).
    #pragma unroll
    for (int it = 0; it < 2; ++it) {
        int eidx = (tid + it * 1024) * 4;       // element index; 4 consecutive n
        float4 wv = *(const float4*)&W[eidx];
        int k  = eidx >> 6;                     // 0..127
        int n0 = eidx & 63;                     // 0,4,..,60
        sh.wt[(n0 + 0) * FIN + (k ^ (((n0 + 0) & 7) << 3))] = f32_to_bf16_rne(wv.x);
        sh.wt[(n0 + 1) * FIN + (k ^ (((n0 + 1) & 7) << 3))] = f32_to_bf16_rne(wv.y);
        sh.wt[(n0 + 2) * FIN + (k ^ (((n0 + 2) & 7) << 3))] = f32_to_bf16_rne(wv.z);
        sh.wt[(n0 + 3) * FIN + (k ^ (((n0 + 3) & 7) << 3))] = f32_to_bf16_rne(wv.w);
    }
    __syncthreads();

    f32x4 acc[4];
    #pragma unroll
    for (int nt = 0; nt < 4; ++nt)
        #pragma unroll
        for (int r = 0; r < 4; ++r) acc[nt][r] = 0.f;

    const bool aok = (arow < N);
    const float* xrow = &x[(size_t)arow * FIN];

    #pragma unroll
    for (int kc = 0; kc < 4; ++kc) {
        float xs[8];
        #pragma unroll
        for (int j = 0; j < 8; ++j) xs[j] = 0.f;
        if (aok) {
            float4 x0 = *(const float4*)&xrow[kc * 32 + q * 8];
            float4 x1 = *(const float4*)&xrow[kc * 32 + q * 8 + 4];
            xs[0] = x0.x; xs[1] = x0.y; xs[2] = x0.z; xs[3] = x0.w;
            xs[4] = x1.x; xs[5] = x1.y; xs[6] = x1.z; xs[7] = x1.w;
        }
        bf16x8 a;
        #pragma unroll
        for (int j = 0; j < 8; ++j) a[j] = (short)f32_to_bf16_rne(xs[j]);

        const int k0 = kc * 32 + q * 8;
        #pragma unroll
        for (int nt = 0; nt < 4; ++nt) {
            bf16x8 b = *(const bf16x8*)
                &sh.wt[(nt * 16 + ln) * FIN + (k0 ^ ((ln & 7) << 3))];
            acc[nt] = __builtin_amdgcn_mfma_f32_16x16x32_bf16(a, b, acc[nt], 0, 0, 0);
        }
    }

    // epilogue: D[m=q*4+reg][n=ln]; scale by t[row]; store bf16
    #pragma unroll
    for (int reg = 0; reg < 4; ++reg) {
        int r = rowb + q * 4 + reg;
        if (r < N) {
            float tv = t[r];
            #pragma unroll
            for (int nt = 0; nt < 4; ++nt)
                support[(size_t)r * FOUT + nt * 16 + ln] =
                    f32_to_bf16_rne(acc[nt][reg] * tv);
        }
    }
}

// ---------------------------------------------------------------------------
// bucket_gather: one block per 32-node bucket (1563 blocks). Sort
// (raw[] stage + count -> wave-0 shfl scan -> reorder), then walk v3:
// each 16-lane group owns 2 WHOLE nodes (no cross-group reduce, no
// divergent store): group accumulates the node's full 64-feature row
// (4 floats/lane), records 4-deep unrolled (16 gathers in flight/wave),
// then 16 lanes store float4 = 256B contiguous. Zero-count nodes fall
// out naturally (empty loop -> bias row). No float atomics normally.
// ---------------------------------------------------------------------------
__global__ __launch_bounds__(256) void bucket_gather_kernel(
    const int* __restrict__ curg, const int2* __restrict__ tmp,
    const ushort* __restrict__ support, const float* __restrict__ bias,
    float* __restrict__ out, const int* __restrict__ ovfc,
    const int4* __restrict__ ovf, int E, int N, int NBUK)
{
    __shared__ int2 raw[CAP];           // 6 KB
    __shared__ int2 sorted[CAP];        // 6 KB
    __shared__ int  cnt[NPB];
    __shared__ int  starts[NPB + 1];
    __shared__ int  cur[NPB];
    __shared__ int  novs;

    const int tid   = threadIdx.x;
    const int w     = tid >> 6;
    const int lane  = tid & 63;
    const int B     = blockIdx.x;
    const int node0 = B * NPB;

    const int base   = B * CAP;
    const int tot    = curg[B];
    const int placed = (tot < CAP) ? tot : CAP;

    if (tid < NPB) cnt[tid] = 0;
    __syncthreads();

    // single global read of the region: stage + count
    for (int i = tid; i < placed; i += 256) {
        int2 r = tmp[base + i];
        raw[i] = r;
        atomicAdd(&cnt[(r.x >> 16) & (NPB - 1)], 1);
    }
    __syncthreads();

    // wave-0 shfl scan over 32 counters
    if (tid < 64) {
        int v   = (tid < NPB) ? cnt[tid] : 0;
        int val = v;
        #pragma unroll
        for (int d = 1; d < NPB; d <<= 1) {
            int n = __shfl_up(val, d);
            if (tid >= d) val += n;
        }
        if (tid < NPB) {
            starts[tid] = val - v;
            cur[tid]    = val - v;
        }
        if (tid == 0) starts[NPB] = placed;
    }
    __syncthreads();

    // reorder LDS -> LDS
    for (int i = tid; i < placed; i += 256) {
        int2 r  = raw[i];
        int pos = atomicAdd(&cur[(r.x >> 16) & (NPB - 1)], 1);
        sorted[pos] = r;
    }
    __syncthreads();

    // ---- walk v3: group g of wave w owns nodes w*8 + g*2 + {0,1} ----
    const int fl = lane & 15;           // feature block 0..15 (4 feats each)
    const int g  = lane >> 4;           // group 0..3
    const float4 bv4 = *(const float4*)&bias[fl * 4];

    #pragma unroll
    for (int sub = 0; sub < 2; ++sub) {
        const int nl = w * 8 + g * 2 + sub;   // node-local 0..31
        const int rb = starts[nl];
        const int re = starts[nl + 1];

        float a0 = 0.f, a1 = 0.f, a2 = 0.f, a3 = 0.f;
        int i = rb;
        for (; i + 4 <= re; i += 4) {          // 4 records in flight
            int2 r0 = sorted[i],     r1 = sorted[i + 1];
            int2 r2 = sorted[i + 2], r3 = sorted[i + 3];
            uint2 u0 = *(const uint2*)&support[(size_t)(r0.x & 0xFFFF) * FOUT + fl * 4];
            uint2 u1 = *(const uint2*)&support[(size_t)(r1.x & 0xFFFF) * FOUT + fl * 4];
            uint2 u2 = *(const uint2*)&support[(size_t)(r2.x & 0xFFFF) * FOUT + fl * 4];
            uint2 u3 = *(const uint2*)&support[(size_t)(r3.x & 0xFFFF) * FOUT + fl * 4];
            float w0 = __int_as_float(r0.y), w1 = __int_as_float(r1.y);
            float w2 = __int_as_float(r2.y), w3 = __int_as_float(r3.y);
            a0 += bf16_to_f32((ushort)(u0.x & 0xFFFFu)) * w0;
            a1 += bf16_to_f32((ushort)(u0.x >> 16)) * w0;
            a2 += bf16_to_f32((ushort)(u0.y & 0xFFFFu)) * w0;
            a3 += bf16_to_f32((ushort)(u0.y >> 16)) * w0;
            a0 += bf16_to_f32((ushort)(u1.x & 0xFFFFu)) * w1;
            a1 += bf16_to_f32((ushort)(u1.x >> 16)) * w1;
            a2 += bf16_to_f32((ushort)(u1.y & 0xFFFFu)) * w1;
            a3 += bf16_to_f32((ushort)(u1.y >> 16)) * w1;
            a0 += bf16_to_f32((ushort)(u2.x & 0xFFFFu)) * w2;
            a1 += bf16_to_f32((ushort)(u2.x >> 16)) * w2;
            a2 += bf16_to_f32((ushort)(u2.y & 0xFFFFu)) * w2;
            a3 += bf16_to_f32((ushort)(u2.y >> 16)) * w2;
            a0 += bf16_to_f32((ushort)(u3.x & 0xFFFFu)) * w3;
            a1 += bf16_to_f32((ushort)(u3.x >> 16)) * w3;
            a2 += bf16_to_f32((ushort)(u3.y & 0xFFFFu)) * w3;
            a3 += bf16_to_f32((ushort)(u3.y >> 16)) * w3;
        }
        for (; i < re; ++i) {
            int2 r = sorted[i];
            uint2 u = *(const uint2*)&support[(size_t)(r.x & 0xFFFF) * FOUT + fl * 4];
            float wg = __int_as_float(r.y);
            a0 += bf16_to_f32((ushort)(u.x & 0xFFFFu)) * wg;
            a1 += bf16_to_f32((ushort)(u.x >> 16)) * wg;
            a2 += bf16_to_f32((ushort)(u.y & 0xFFFFu)) * wg;
            a3 += bf16_to_f32((ushort)(u.y >> 16)) * wg;
        }
        const int node = node0 + nl;
        if (node < N) {
            float4 o;
            o.x = a0 + bv4.x; o.y = a1 + bv4.y;
            o.z = a2 + bv4.z; o.w = a3 + bv4.w;
            *(float4*)&out[(size_t)node * FOUT + fl * 4] = o;
        }
    }

    // overflow tail: never taken at this size; kept for correctness.
    __syncthreads();
    if (tid == 0) novs = *ovfc;
    __syncthreads();
    int nov = novs;
    if (nov > 0) {
        if (nov > E) nov = E;
        __threadfence();
        for (int k = w; k < nov; k += 4) {
            int4 r = ovf[k];
            if (r.z == B) {
                int node = node0 + ((r.x >> 16) & (NPB - 1));
                if (node < N) {
                    float v = bf16_to_f32(
                        support[(size_t)(r.x & 0xFFFF) * FOUT + lane]);
                    atomicAdd(&out[(size_t)node * FOUT + lane],
                              v * __int_as_float(r.y));
                }
            }
        }
    }
}

extern "C" void kernel_launch(void* const* d_in, const int* in_sizes, int n_in,
                              void* d_out, int out_size, void* d_ws, size_t ws_size,
                              hipStream_t stream) {
    const float* x    = (const float*)d_in[0];
    const float* t    = (const float*)d_in[1];
    const int*   src  = (const int*)d_in[2];
    const int*   dst  = (const int*)d_in[3];
    const float* ev   = (const float*)d_in[4];
    const float* W    = (const float*)d_in[5];
    const float* bias = (const float*)d_in[6];
    float* out = (float*)d_out;

    const int N = in_sizes[1];   // 50000
    const int E = in_sizes[2];   // 800000

    char*   ws      = (char*)d_ws;
    ushort* support = (ushort*)ws;
    int*    cur     = (int*)(ws + OFF_CUR);
    int*    ovfc    = (int*)(ws + OFF_OVFC);
    int2*   tmp     = (int2*)(ws + OFF_TMP);
    int4*   ovf     = (int4*)(ws + OFF_OVF);

    const int GB   = (N + TILE_ROWS - 1) / TILE_ROWS;       // 196
    const int SBP  = (E + EPB - 1) / EPB;                   // 98
    const int NBUK = (N + NPB - 1) / NPB;                   // 1563

    // zero bucket cursors + overflow count (6.5 KB, graph-capturable)
    hipMemsetAsync(ws + OFF_CUR, 0, OFF_TMP - OFF_CUR, stream);

    // 1) fused independent branches (1024-thread blocks): gemm || scatter
    gemm_scatter_kernel<<<GB + SBP, 1024, 0, stream>>>(
        x, t, W, support, N, src, dst, ev, cur, tmp, ovfc, ovf,
        E, SBP, NBUK, GB);

    // 2) per-bucket sort + group-per-node walk -> out (+bias)
    bucket_gather_kernel<<<NBUK, 256, 0, stream>>>(
        cur, tmp, support, bias, out, ovfc, ovf, E, N, NBUK);
}

// Round 13
// 123.185 us; speedup vs baseline: 1.1345x; 1.0290x over previous
//
#include <hip/hip_runtime.h>
#include <hip/hip_bf16.h>

#define FIN 128
#define FOUT 64
#define TILE_ROWS 256      // rows per gemm block = 16 waves x 16

#define EPB 8192           // edges per scatter chunk (98 blocks x 16 waves)
#define NPB 32             // nodes per bucket (d >> 5)
#define NBUK_MAX 1600
#define CAP 768            // records per bucket region (mean 512, +11 sigma)
#define NCAP 48            // LDS record slots per node (mean 16, +8 sigma)

// Workspace layout (bytes), ws >= 268 MB:
//   [0, 6,400,000)         support : N*64 bf16
//   OFF_CUR   +6,400       cur     : NBUK int (bucket fill counters)
//   OFF_OVFC  +64          ovfc    : 1 int (overflow count)
//   OFF_TMP   +9,830,400   tmp     : NBUK_MAX*CAP int2 regions {src|dloc<<16, ev}
//   OFF_OVF   +12,800,000  ovf     : E int4 {recx, recy, bucket, pad}
#define OFF_CUR   6400000
#define OFF_OVFC  6406400
#define OFF_TMP   6406464
#define OFF_OVF   16236864

typedef short bf16x8 __attribute__((ext_vector_type(8)));
typedef float f32x4  __attribute__((ext_vector_type(4)));

__device__ inline ushort f32_to_bf16_rne(float f) {
    unsigned u = __float_as_uint(f);
    u += 0x7FFFu + ((u >> 16) & 1u);
    return (ushort)(u >> 16);
}
__device__ inline float bf16_to_f32(ushort h) {
    return __uint_as_float((unsigned)h << 16);
}

// ---------------------------------------------------------------------------
// Fused, independent branches, 1024-thread blocks (no fences) -- R12 k1,
// unchanged:
//   blocks [0,GB):       MFMA gemm, 256-row tiles (16 waves x 16 rows)
//   blocks [GB,GB+SBP):  scatter chunk EPB=8192, 16 waves/block: R10-level
//                        parallelism (1568 scatter waves) AND ~5.2-record
//                        runs -> write-combined tmp stores (R11: 21MB).
// rec = {src | (d&31)<<16, ev_bits}   (src < 65536: N = 50000 ok)
// NOTE (R8): never use fp LDS atomics on gfx950 (308us RMW stall).
// NOTE (R9/R11): keep scatter waves ~1500+; few-wave configs tail out.
// ---------------------------------------------------------------------------
union __align__(16) K1Sh {
    ushort wt[FOUT * FIN];                            // 16 KB (gemm)
    struct { int h[NBUK_MAX]; int c[NBUK_MAX]; } sc;  // 12.8 KB (scatter)
};

__global__ __launch_bounds__(1024) void gemm_scatter_kernel(
    const float* __restrict__ x, const float* __restrict__ t,
    const float* __restrict__ W, ushort* __restrict__ support, int N,
    const int* __restrict__ src, const int* __restrict__ dst,
    const float* __restrict__ ev, int* __restrict__ cur,
    int2* __restrict__ tmp, int* __restrict__ ovfc, int4* __restrict__ ovf,
    int E, int SBP, int NBUK, int GB)
{
    __shared__ K1Sh sh;
    const int tid = threadIdx.x;

    if (blockIdx.x >= (unsigned)GB) {
        // ---- scatter branch: 16 waves, EPB 8192 ----
        const int chunk = blockIdx.x - GB;
        const int e0    = chunk * EPB;

        for (int i = tid; i < NBUK; i += 1024) sh.sc.h[i] = 0;
        __syncthreads();

        // pass 1: local bucket counts (8 edges/thread)
        for (int i = tid; i < EPB; i += 1024) {
            int e = e0 + i;
            if (e < E) atomicAdd(&sh.sc.h[dst[e] >> 5], 1);
        }
        __syncthreads();

        // pass 2: reserve contiguous slices of bucket regions
        for (int j = tid; j < NBUK; j += 1024) {
            int hj = sh.sc.h[j];
            if (hj) sh.sc.c[j] = atomicAdd(&cur[j], hj);
        }
        __syncthreads();

        // pass 3: place (dst re-read is L2-hot); ~5.2-record runs per bucket
        for (int i = tid; i < EPB; i += 1024) {
            int e = e0 + i;
            if (e < E) {
                int d = dst[e];
                int j = d >> 5;
                int s = atomicAdd(&sh.sc.c[j], 1);
                int2 rec = make_int2(src[e] | ((d & (NPB - 1)) << 16),
                                     __float_as_int(ev[e]));
                if (s < CAP) {
                    tmp[(size_t)j * CAP + s] = rec;
                } else {                 // never at this size; kept correct
                    int o = atomicAdd(ovfc, 1);
                    if (o < E) ovf[o] = make_int4(rec.x, rec.y, j, 0);
                }
            }
        }
        return;
    }

    // ---- MFMA gemm branch: 256-row tile, 16 waves x 16 rows ----
    const int gb   = blockIdx.x;
    const int lane = tid & 63;
    const int w    = tid >> 6;          // wave 0..15
    const int ln   = lane & 15;
    const int q    = lane >> 4;         // quad 0..3
    const int rowb = gb * TILE_ROWS + w * 16;
    const int arow = rowb + ln;

    // Stage W -> LDS bf16, transposed WT[n][k]; 16B slot XOR-swizzled by n&7.
    #pragma unroll
    for (int it = 0; it < 2; ++it) {
        int eidx = (tid + it * 1024) * 4;       // element index; 4 consecutive n
        float4 wv = *(const float4*)&W[eidx];
        int k  = eidx >> 6;                     // 0..127
        int n0 = eidx & 63;                     // 0,4,..,60
        sh.wt[(n0 + 0) * FIN + (k ^ (((n0 + 0) & 7) << 3))] = f32_to_bf16_rne(wv.x);
        sh.wt[(n0 + 1) * FIN + (k ^ (((n0 + 1) & 7) << 3))] = f32_to_bf16_rne(wv.y);
        sh.wt[(n0 + 2) * FIN + (k ^ (((n0 + 2) & 7) << 3))] = f32_to_bf16_rne(wv.z);
        sh.wt[(n0 + 3) * FIN + (k ^ (((n0 + 3) & 7) << 3))] = f32_to_bf16_rne(wv.w);
    }
    __syncthreads();

    f32x4 acc[4];
    #pragma unroll
    for (int nt = 0; nt < 4; ++nt)
        #pragma unroll
        for (int r = 0; r < 4; ++r) acc[nt][r] = 0.f;

    const bool aok = (arow < N);
    const float* xrow = &x[(size_t)arow * FIN];

    #pragma unroll
    for (int kc = 0; kc < 4; ++kc) {
        float xs[8];
        #pragma unroll
        for (int j = 0; j < 8; ++j) xs[j] = 0.f;
        if (aok) {
            float4 x0 = *(const float4*)&xrow[kc * 32 + q * 8];
            float4 x1 = *(const float4*)&xrow[kc * 32 + q * 8 + 4];
            xs[0] = x0.x; xs[1] = x0.y; xs[2] = x0.z; xs[3] = x0.w;
            xs[4] = x1.x; xs[5] = x1.y; xs[6] = x1.z; xs[7] = x1.w;
        }
        bf16x8 a;
        #pragma unroll
        for (int j = 0; j < 8; ++j) a[j] = (short)f32_to_bf16_rne(xs[j]);

        const int k0 = kc * 32 + q * 8;
        #pragma unroll
        for (int nt = 0; nt < 4; ++nt) {
            bf16x8 b = *(const bf16x8*)
                &sh.wt[(nt * 16 + ln) * FIN + (k0 ^ ((ln & 7) << 3))];
            acc[nt] = __builtin_amdgcn_mfma_f32_16x16x32_bf16(a, b, acc[nt], 0, 0, 0);
        }
    }

    // epilogue: D[m=q*4+reg][n=ln]; scale by t[row]; store bf16
    #pragma unroll
    for (int reg = 0; reg < 4; ++reg) {
        int r = rowb + q * 4 + reg;
        if (r < N) {
            float tv = t[r];
            #pragma unroll
            for (int nt = 0; nt < 4; ++nt)
                support[(size_t)r * FOUT + nt * 16 + ln] =
                    f32_to_bf16_rne(acc[nt][reg] * tv);
        }
    }
}

// ---------------------------------------------------------------------------
// bucket_gather v4: single-pass direct-claim sort. One block per 32-node
// bucket. Each node gets a FIXED 48-slot LDS region; the one global-read
// pass claims a slot via LDS int atomic on cnt[node] and writes the record
// directly there. Removes raw[] staging, the wave-0 scan, and the reorder
// pass (~60% of the old sort's LDS traffic/atomics, 2 barriers).
// Walk v3 unchanged: group g of wave w owns 2 whole nodes; 4 records in
// flight; 16 lanes x uint2 = full 128B support row per record; float4 store.
// Per-node overflow (P ~ 1e-13/node): node recomputed serially from the
// L2-hot region. Region overflow (ovf): unchanged atomic tail.
// ---------------------------------------------------------------------------
__global__ __launch_bounds__(256) void bucket_gather_kernel(
    const int* __restrict__ curg, const int2* __restrict__ tmp,
    const ushort* __restrict__ support, const float* __restrict__ bias,
    float* __restrict__ out, const int* __restrict__ ovfc,
    const int4* __restrict__ ovf, int E, int N, int NBUK)
{
    __shared__ int2 sorted[NPB * NCAP];   // 12.3 KB
    __shared__ int  cnt[NPB];
    __shared__ int  novs;

    const int tid   = threadIdx.x;
    const int w     = tid >> 6;
    const int lane  = tid & 63;
    const int B     = blockIdx.x;
    const int node0 = B * NPB;

    const int base   = B * CAP;
    const int tot    = curg[B];
    const int placed = (tot < CAP) ? tot : CAP;

    if (tid < NPB) cnt[tid] = 0;
    __syncthreads();

    // single pass: global read -> claim slot -> direct place
    for (int i = tid; i < placed; i += 256) {
        int2 r = tmp[base + i];
        int nl = (r.x >> 16) & (NPB - 1);
        int s  = atomicAdd(&cnt[nl], 1);
        if (s < NCAP) sorted[nl * NCAP + s] = r;
        // dropped slots handled by per-node overflow recompute below
    }
    __syncthreads();

    // ---- walk v3: group g of wave w owns nodes w*8 + g*2 + {0,1} ----
    const int fl = lane & 15;           // feature block 0..15 (4 feats each)
    const int g  = lane >> 4;           // group 0..3
    const float4 bv4 = *(const float4*)&bias[fl * 4];

    #pragma unroll
    for (int sub = 0; sub < 2; ++sub) {
        const int nl = w * 8 + g * 2 + sub;   // node-local 0..31
        const int c  = cnt[nl];
        if (c > NCAP) continue;               // group-uniform; serial path below
        const int rb = nl * NCAP;
        const int re = rb + c;

        float a0 = 0.f, a1 = 0.f, a2 = 0.f, a3 = 0.f;
        int i = rb;
        for (; i + 4 <= re; i += 4) {          // 4 records in flight
            int2 r0 = sorted[i],     r1 = sorted[i + 1];
            int2 r2 = sorted[i + 2], r3 = sorted[i + 3];
            uint2 u0 = *(const uint2*)&support[(size_t)(r0.x & 0xFFFF) * FOUT + fl * 4];
            uint2 u1 = *(const uint2*)&support[(size_t)(r1.x & 0xFFFF) * FOUT + fl * 4];
            uint2 u2 = *(const uint2*)&support[(size_t)(r2.x & 0xFFFF) * FOUT + fl * 4];
            uint2 u3 = *(const uint2*)&support[(size_t)(r3.x & 0xFFFF) * FOUT + fl * 4];
            float w0 = __int_as_float(r0.y), w1 = __int_as_float(r1.y);
            float w2 = __int_as_float(r2.y), w3 = __int_as_float(r3.y);
            a0 += bf16_to_f32((ushort)(u0.x & 0xFFFFu)) * w0;
            a1 += bf16_to_f32((ushort)(u0.x >> 16)) * w0;
            a2 += bf16_to_f32((ushort)(u0.y & 0xFFFFu)) * w0;
            a3 += bf16_to_f32((ushort)(u0.y >> 16)) * w0;
            a0 += bf16_to_f32((ushort)(u1.x & 0xFFFFu)) * w1;
            a1 += bf16_to_f32((ushort)(u1.x >> 16)) * w1;
            a2 += bf16_to_f32((ushort)(u1.y & 0xFFFFu)) * w1;
            a3 += bf16_to_f32((ushort)(u1.y >> 16)) * w1;
            a0 += bf16_to_f32((ushort)(u2.x & 0xFFFFu)) * w2;
            a1 += bf16_to_f32((ushort)(u2.x >> 16)) * w2;
            a2 += bf16_to_f32((ushort)(u2.y & 0xFFFFu)) * w2;
            a3 += bf16_to_f32((ushort)(u2.y >> 16)) * w2;
            a0 += bf16_to_f32((ushort)(u3.x & 0xFFFFu)) * w3;
            a1 += bf16_to_f32((ushort)(u3.x >> 16)) * w3;
            a2 += bf16_to_f32((ushort)(u3.y & 0xFFFFu)) * w3;
            a3 += bf16_to_f32((ushort)(u3.y >> 16)) * w3;
        }
        for (; i < re; ++i) {
            int2 r = sorted[i];
            uint2 u = *(const uint2*)&support[(size_t)(r.x & 0xFFFF) * FOUT + fl * 4];
            float wg = __int_as_float(r.y);
            a0 += bf16_to_f32((ushort)(u.x & 0xFFFFu)) * wg;
            a1 += bf16_to_f32((ushort)(u.x >> 16)) * wg;
            a2 += bf16_to_f32((ushort)(u.y & 0xFFFFu)) * wg;
            a3 += bf16_to_f32((ushort)(u.y >> 16)) * wg;
        }
        const int node = node0 + nl;
        if (node < N) {
            float4 o;
            o.x = a0 + bv4.x; o.y = a1 + bv4.y;
            o.z = a2 + bv4.z; o.w = a3 + bv4.w;
            *(float4*)&out[(size_t)node * FOUT + fl * 4] = o;
        }
    }
    __syncthreads();

    // per-node overflow recompute: never taken (P ~ 5e-9 total); block-uniform
    for (int nl = 0; nl < NPB; ++nl) {
        if (cnt[nl] > NCAP) {
            const int node = node0 + nl;
            if (tid < 16 && node < N) {
                float a0 = 0.f, a1 = 0.f, a2 = 0.f, a3 = 0.f;
                for (int i = 0; i < placed; ++i) {
                    int2 r = tmp[base + i];
                    if (((r.x >> 16) & (NPB - 1)) == nl) {
                        uint2 u = *(const uint2*)
                            &support[(size_t)(r.x & 0xFFFF) * FOUT + tid * 4];
                        float wg = __int_as_float(r.y);
                        a0 += bf16_to_f32((ushort)(u.x & 0xFFFFu)) * wg;
                        a1 += bf16_to_f32((ushort)(u.x >> 16)) * wg;
                        a2 += bf16_to_f32((ushort)(u.y & 0xFFFFu)) * wg;
                        a3 += bf16_to_f32((ushort)(u.y >> 16)) * wg;
                    }
                }
                float4 o;
                o.x = a0 + bias[tid * 4 + 0]; o.y = a1 + bias[tid * 4 + 1];
                o.z = a2 + bias[tid * 4 + 2]; o.w = a3 + bias[tid * 4 + 3];
                *(float4*)&out[(size_t)node * FOUT + tid * 4] = o;
            }
        }
    }

    // region-overflow tail: never taken at this size; kept for correctness.
    __syncthreads();
    if (tid == 0) novs = *ovfc;
    __syncthreads();
    int nov = novs;
    if (nov > 0) {
        if (nov > E) nov = E;
        __threadfence();
        for (int k = w; k < nov; k += 4) {
            int4 r = ovf[k];
            if (r.z == B) {
                int node = node0 + ((r.x >> 16) & (NPB - 1));
                if (node < N) {
                    float v = bf16_to_f32(
                        support[(size_t)(r.x & 0xFFFF) * FOUT + lane]);
                    atomicAdd(&out[(size_t)node * FOUT + lane],
                              v * __int_as_float(r.y));
                }
            }
        }
    }
}

extern "C" void kernel_launch(void* const* d_in, const int* in_sizes, int n_in,
                              void* d_out, int out_size, void* d_ws, size_t ws_size,
                              hipStream_t stream) {
    const float* x    = (const float*)d_in[0];
    const float* t    = (const float*)d_in[1];
    const int*   src  = (const int*)d_in[2];
    const int*   dst  = (const int*)d_in[3];
    const float* ev   = (const float*)d_in[4];
    const float* W    = (const float*)d_in[5];
    const float* bias = (const float*)d_in[6];
    float* out = (float*)d_out;

    const int N = in_sizes[1];   // 50000
    const int E = in_sizes[2];   // 800000

    char*   ws      = (char*)d_ws;
    ushort* support = (ushort*)ws;
    int*    cur     = (int*)(ws + OFF_CUR);
    int*    ovfc    = (int*)(ws + OFF_OVFC);
    int2*   tmp     = (int2*)(ws + OFF_TMP);
    int4*   ovf     = (int4*)(ws + OFF_OVF);

    const int GB   = (N + TILE_ROWS - 1) / TILE_ROWS;       // 196
    const int SBP  = (E + EPB - 1) / EPB;                   // 98
    const int NBUK = (N + NPB - 1) / NPB;                   // 1563

    // zero bucket cursors + overflow count (6.5 KB, graph-capturable)
    hipMemsetAsync(ws + OFF_CUR, 0, OFF_TMP - OFF_CUR, stream);

    // 1) fused independent branches (1024-thread blocks): gemm || scatter
    gemm_scatter_kernel<<<GB + SBP, 1024, 0, stream>>>(
        x, t, W, support, N, src, dst, ev, cur, tmp, ovfc, ovf,
        E, SBP, NBUK, GB);

    // 2) per-bucket direct-claim sort + group-per-node walk -> out (+bias)
    bucket_gather_kernel<<<NBUK, 256, 0, stream>>>(
        cur, tmp, support, bias, out, ovfc, ovf, E, N, NBUK);
}

// Round 14
// 117.909 us; speedup vs baseline: 1.1853x; 1.0448x over previous
//
#include <hip/hip_runtime.h>
#include <hip/hip_bf16.h>

#define FIN 128
#define FOUT 64
#define TILE_ROWS 256      // rows per gemm block = 16 waves x 16

#define EPB 8192           // edges per scatter chunk (98 blocks x 16 waves)
#define NPB 32             // nodes per bucket (d >> 5)
#define NBUK_MAX 1600
#define CAP 768            // records per bucket region (mean 512, +11 sigma)
#define NCAP 48            // LDS record slots per node (mean 16, +8 sigma)

// Workspace layout (bytes), ws >= 268 MB:
//   [0, 6,400,000)         support : N*64 bf16
//   OFF_CUR   +6,400       cur     : NBUK int (bucket fill counters)
//   OFF_OVFC  +64          ovfc    : 1 int (overflow count)
//   OFF_TMP   +9,830,400   tmp     : NBUK_MAX*CAP int2 regions {src|dloc<<16, ev}
//   OFF_OVF   +12,800,000  ovf     : E int4 {recx, recy, bucket, pad}
#define OFF_CUR   6400000
#define OFF_OVFC  6406400
#define OFF_TMP   6406464
#define OFF_OVF   16236864

typedef short bf16x8 __attribute__((ext_vector_type(8)));
typedef float f32x4  __attribute__((ext_vector_type(4)));

__device__ inline ushort f32_to_bf16_rne(float f) {
    unsigned u = __float_as_uint(f);
    u += 0x7FFFu + ((u >> 16) & 1u);
    return (ushort)(u >> 16);
}
__device__ inline float bf16_to_f32(ushort h) {
    return __uint_as_float((unsigned)h << 16);
}

// ---------------------------------------------------------------------------
// Fused, independent branches, 1024-thread blocks (no fences):
//   blocks [0,GB):       MFMA gemm, 256-row tiles (16 waves x 16 rows)
//   blocks [GB,GB+SBP):  scatter chunk EPB=8192, 16 waves/block, with
//                        REGISTER-HELD records: pass1 loads dst/src/ev once
//                        into rec[8]/bk[8] (statically indexed), pass3 only
//                        claims the LDS cursor and stores -- no global
//                        re-reads on the critical path.
// rec = {src | (d&31)<<16, ev_bits}   (src < 65536: N = 50000 ok)
// NOTE (R8): never use fp LDS atomics on gfx950 (308us RMW stall).
// NOTE (R9/R11): keep scatter waves ~1500+; few-wave configs tail out.
// ---------------------------------------------------------------------------
union __align__(16) K1Sh {
    ushort wt[FOUT * FIN];                            // 16 KB (gemm)
    struct { int h[NBUK_MAX]; int c[NBUK_MAX]; } sc;  // 12.8 KB (scatter)
};

__global__ __launch_bounds__(1024) void gemm_scatter_kernel(
    const float* __restrict__ x, const float* __restrict__ t,
    const float* __restrict__ W, ushort* __restrict__ support, int N,
    const int* __restrict__ src, const int* __restrict__ dst,
    const float* __restrict__ ev, int* __restrict__ cur,
    int2* __restrict__ tmp, int* __restrict__ ovfc, int4* __restrict__ ovf,
    int E, int SBP, int NBUK, int GB)
{
    __shared__ K1Sh sh;
    const int tid = threadIdx.x;

    if (blockIdx.x >= (unsigned)GB) {
        // ---- scatter branch: 16 waves, EPB 8192, 8 edges/thread in regs ----
        const int chunk = blockIdx.x - GB;
        const int e0    = chunk * EPB;

        for (int i = tid; i < NBUK; i += 1024) sh.sc.h[i] = 0;
        __syncthreads();

        // pass 1: load once -> registers; count buckets
        int2 rec[8];
        int  bk[8];
        #pragma unroll
        for (int u = 0; u < 8; ++u) {
            int e = e0 + tid + u * 1024;
            bk[u] = -1;
            if (e < E) {
                int d = dst[e];
                bk[u]  = d >> 5;
                rec[u] = make_int2(src[e] | ((d & (NPB - 1)) << 16),
                                   __float_as_int(ev[e]));
                atomicAdd(&sh.sc.h[bk[u]], 1);
            }
        }
        __syncthreads();

        // pass 2: reserve contiguous slices of bucket regions
        for (int j = tid; j < NBUK; j += 1024) {
            int hj = sh.sc.h[j];
            if (hj) sh.sc.c[j] = atomicAdd(&cur[j], hj);
        }
        __syncthreads();

        // pass 3: claim LDS cursor, store register-held record
        #pragma unroll
        for (int u = 0; u < 8; ++u) {
            if (bk[u] >= 0) {
                int s = atomicAdd(&sh.sc.c[bk[u]], 1);
                if (s < CAP) {
                    tmp[(size_t)bk[u] * CAP + s] = rec[u];
                } else {                 // never at this size; kept correct
                    int o = atomicAdd(ovfc, 1);
                    if (o < E) ovf[o] = make_int4(rec[u].x, rec[u].y, bk[u], 0);
                }
            }
        }
        return;
    }

    // ---- MFMA gemm branch: 256-row tile, 16 waves x 16 rows ----
    const int gb   = blockIdx.x;
    const int lane = tid & 63;
    const int w    = tid >> 6;          // wave 0..15
    const int ln   = lane & 15;
    const int q    = lane >> 4;         // quad 0..3
    const int rowb = gb * TILE_ROWS + w * 16;
    const int arow = rowb + ln;

    // Stage W -> LDS bf16, transposed WT[n][k]; 16B slot XOR-swizzled by n&7.
    #pragma unroll
    for (int it = 0; it < 2; ++it) {
        int eidx = (tid + it * 1024) * 4;       // element index; 4 consecutive n
        float4 wv = *(const float4*)&W[eidx];
        int k  = eidx >> 6;                     // 0..127
        int n0 = eidx & 63;                     // 0,4,..,60
        sh.wt[(n0 + 0) * FIN + (k ^ (((n0 + 0) & 7) << 3))] = f32_to_bf16_rne(wv.x);
        sh.wt[(n0 + 1) * FIN + (k ^ (((n0 + 1) & 7) << 3))] = f32_to_bf16_rne(wv.y);
        sh.wt[(n0 + 2) * FIN + (k ^ (((n0 + 2) & 7) << 3))] = f32_to_bf16_rne(wv.z);
        sh.wt[(n0 + 3) * FIN + (k ^ (((n0 + 3) & 7) << 3))] = f32_to_bf16_rne(wv.w);
    }
    __syncthreads();

    f32x4 acc[4];
    #pragma unroll
    for (int nt = 0; nt < 4; ++nt)
        #pragma unroll
        for (int r = 0; r < 4; ++r) acc[nt][r] = 0.f;

    const bool aok = (arow < N);
    const float* xrow = &x[(size_t)arow * FIN];

    #pragma unroll
    for (int kc = 0; kc < 4; ++kc) {
        float xs[8];
        #pragma unroll
        for (int j = 0; j < 8; ++j) xs[j] = 0.f;
        if (aok) {
            float4 x0 = *(const float4*)&xrow[kc * 32 + q * 8];
            float4 x1 = *(const float4*)&xrow[kc * 32 + q * 8 + 4];
            xs[0] = x0.x; xs[1] = x0.y; xs[2] = x0.z; xs[3] = x0.w;
            xs[4] = x1.x; xs[5] = x1.y; xs[6] = x1.z; xs[7] = x1.w;
        }
        bf16x8 a;
        #pragma unroll
        for (int j = 0; j < 8; ++j) a[j] = (short)f32_to_bf16_rne(xs[j]);

        const int k0 = kc * 32 + q * 8;
        #pragma unroll
        for (int nt = 0; nt < 4; ++nt) {
            bf16x8 b = *(const bf16x8*)
                &sh.wt[(nt * 16 + ln) * FIN + (k0 ^ ((ln & 7) << 3))];
            acc[nt] = __builtin_amdgcn_mfma_f32_16x16x32_bf16(a, b, acc[nt], 0, 0, 0);
        }
    }

    // epilogue: D[m=q*4+reg][n=ln]; scale by t[row]; store bf16
    #pragma unroll
    for (int reg = 0; reg < 4; ++reg) {
        int r = rowb + q * 4 + reg;
        if (r < N) {
            float tv = t[r];
            #pragma unroll
            for (int nt = 0; nt < 4; ++nt)
                support[(size_t)r * FOUT + nt * 16 + ln] =
                    f32_to_bf16_rne(acc[nt][reg] * tv);
        }
    }
}

// ---------------------------------------------------------------------------
// bucket_gather v4 + 8-deep walk: single-pass direct-claim sort (fixed
// 48-slot LDS region per node; one LDS atomic claims the slot); then walk:
// group g of wave w owns 2 whole nodes; EIGHT records in flight per group
// (32 gathers/wave outstanding), full 128B support row per record via
// 16 lanes x uint2; float4 store (+bias). Per-node overflow (P~1e-13):
// serial recompute from L2-hot region. Region overflow: atomic tail.
// ---------------------------------------------------------------------------
__global__ __launch_bounds__(256) void bucket_gather_kernel(
    const int* __restrict__ curg, const int2* __restrict__ tmp,
    const ushort* __restrict__ support, const float* __restrict__ bias,
    float* __restrict__ out, const int* __restrict__ ovfc,
    const int4* __restrict__ ovf, int E, int N, int NBUK)
{
    __shared__ int2 sorted[NPB * NCAP];   // 12.3 KB
    __shared__ int  cnt[NPB];
    __shared__ int  novs;

    const int tid   = threadIdx.x;
    const int w     = tid >> 6;
    const int lane  = tid & 63;
    const int B     = blockIdx.x;
    const int node0 = B * NPB;

    const int base   = B * CAP;
    const int tot    = curg[B];
    const int placed = (tot < CAP) ? tot : CAP;

    if (tid < NPB) cnt[tid] = 0;
    __syncthreads();

    // single pass: global read -> claim slot -> direct place
    for (int i = tid; i < placed; i += 256) {
        int2 r = tmp[base + i];
        int nl = (r.x >> 16) & (NPB - 1);
        int s  = atomicAdd(&cnt[nl], 1);
        if (s < NCAP) sorted[nl * NCAP + s] = r;
    }
    __syncthreads();

    // ---- walk: group g of wave w owns nodes w*8 + g*2 + {0,1} ----
    const int fl = lane & 15;           // feature block 0..15 (4 feats each)
    const int g  = lane >> 4;           // group 0..3
    const float4 bv4 = *(const float4*)&bias[fl * 4];

    #pragma unroll
    for (int sub = 0; sub < 2; ++sub) {
        const int nl = w * 8 + g * 2 + sub;   // node-local 0..31
        const int c  = cnt[nl];
        if (c > NCAP) continue;               // group-uniform; serial path below
        const int rb = nl * NCAP;
        const int re = rb + c;

        float a0 = 0.f, a1 = 0.f, a2 = 0.f, a3 = 0.f;
        int i = rb;
        for (; i + 8 <= re; i += 8) {          // 8 records in flight
            int2 rr[8];
            #pragma unroll
            for (int u = 0; u < 8; ++u) rr[u] = sorted[i + u];
            uint2 uu[8];
            #pragma unroll
            for (int u = 0; u < 8; ++u)
                uu[u] = *(const uint2*)
                    &support[(size_t)(rr[u].x & 0xFFFF) * FOUT + fl * 4];
            #pragma unroll
            for (int u = 0; u < 8; ++u) {
                float wg = __int_as_float(rr[u].y);
                a0 += bf16_to_f32((ushort)(uu[u].x & 0xFFFFu)) * wg;
                a1 += bf16_to_f32((ushort)(uu[u].x >> 16)) * wg;
                a2 += bf16_to_f32((ushort)(uu[u].y & 0xFFFFu)) * wg;
                a3 += bf16_to_f32((ushort)(uu[u].y >> 16)) * wg;
            }
        }
        for (; i + 4 <= re; i += 4) {          // 4 records in flight
            int2 r0 = sorted[i],     r1 = sorted[i + 1];
            int2 r2 = sorted[i + 2], r3 = sorted[i + 3];
            uint2 u0 = *(const uint2*)&support[(size_t)(r0.x & 0xFFFF) * FOUT + fl * 4];
            uint2 u1 = *(const uint2*)&support[(size_t)(r1.x & 0xFFFF) * FOUT + fl * 4];
            uint2 u2 = *(const uint2*)&support[(size_t)(r2.x & 0xFFFF) * FOUT + fl * 4];
            uint2 u3 = *(const uint2*)&support[(size_t)(r3.x & 0xFFFF) * FOUT + fl * 4];
            float w0 = __int_as_float(r0.y), w1 = __int_as_float(r1.y);
            float w2 = __int_as_float(r2.y), w3 = __int_as_float(r3.y);
            a0 += bf16_to_f32((ushort)(u0.x & 0xFFFFu)) * w0;
            a1 += bf16_to_f32((ushort)(u0.x >> 16)) * w0;
            a2 += bf16_to_f32((ushort)(u0.y & 0xFFFFu)) * w0;
            a3 += bf16_to_f32((ushort)(u0.y >> 16)) * w0;
            a0 += bf16_to_f32((ushort)(u1.x & 0xFFFFu)) * w1;
            a1 += bf16_to_f32((ushort)(u1.x >> 16)) * w1;
            a2 += bf16_to_f32((ushort)(u1.y & 0xFFFFu)) * w1;
            a3 += bf16_to_f32((ushort)(u1.y >> 16)) * w1;
            a0 += bf16_to_f32((ushort)(u2.x & 0xFFFFu)) * w2;
            a1 += bf16_to_f32((ushort)(u2.x >> 16)) * w2;
            a2 += bf16_to_f32((ushort)(u2.y & 0xFFFFu)) * w2;
            a3 += bf16_to_f32((ushort)(u2.y >> 16)) * w2;
            a0 += bf16_to_f32((ushort)(u3.x & 0xFFFFu)) * w3;
            a1 += bf16_to_f32((ushort)(u3.x >> 16)) * w3;
            a2 += bf16_to_f32((ushort)(u3.y & 0xFFFFu)) * w3;
            a3 += bf16_to_f32((ushort)(u3.y >> 16)) * w3;
        }
        for (; i < re; ++i) {
            int2 r = sorted[i];
            uint2 u = *(const uint2*)&support[(size_t)(r.x & 0xFFFF) * FOUT + fl * 4];
            float wg = __int_as_float(r.y);
            a0 += bf16_to_f32((ushort)(u.x & 0xFFFFu)) * wg;
            a1 += bf16_to_f32((ushort)(u.x >> 16)) * wg;
            a2 += bf16_to_f32((ushort)(u.y & 0xFFFFu)) * wg;
            a3 += bf16_to_f32((ushort)(u.y >> 16)) * wg;
        }
        const int node = node0 + nl;
        if (node < N) {
            float4 o;
            o.x = a0 + bv4.x; o.y = a1 + bv4.y;
            o.z = a2 + bv4.z; o.w = a3 + bv4.w;
            *(float4*)&out[(size_t)node * FOUT + fl * 4] = o;
        }
    }
    __syncthreads();

    // per-node overflow recompute: never taken (P ~ 5e-9 total); block-uniform
    for (int nl = 0; nl < NPB; ++nl) {
        if (cnt[nl] > NCAP) {
            const int node = node0 + nl;
            if (tid < 16 && node < N) {
                float a0 = 0.f, a1 = 0.f, a2 = 0.f, a3 = 0.f;
                for (int i = 0; i < placed; ++i) {
                    int2 r = tmp[base + i];
                    if (((r.x >> 16) & (NPB - 1)) == nl) {
                        uint2 u = *(const uint2*)
                            &support[(size_t)(r.x & 0xFFFF) * FOUT + tid * 4];
                        float wg = __int_as_float(r.y);
                        a0 += bf16_to_f32((ushort)(u.x & 0xFFFFu)) * wg;
                        a1 += bf16_to_f32((ushort)(u.x >> 16)) * wg;
                        a2 += bf16_to_f32((ushort)(u.y & 0xFFFFu)) * wg;
                        a3 += bf16_to_f32((ushort)(u.y >> 16)) * wg;
                    }
                }
                float4 o;
                o.x = a0 + bias[tid * 4 + 0]; o.y = a1 + bias[tid * 4 + 1];
                o.z = a2 + bias[tid * 4 + 2]; o.w = a3 + bias[tid * 4 + 3];
                *(float4*)&out[(size_t)node * FOUT + tid * 4] = o;
            }
        }
    }

    // region-overflow tail: never taken at this size; kept for correctness.
    __syncthreads();
    if (tid == 0) novs = *ovfc;
    __syncthreads();
    int nov = novs;
    if (nov > 0) {
        if (nov > E) nov = E;
        __threadfence();
        for (int k = w; k < nov; k += 4) {
            int4 r = ovf[k];
            if (r.z == B) {
                int node = node0 + ((r.x >> 16) & (NPB - 1));
                if (node < N) {
                    float v = bf16_to_f32(
                        support[(size_t)(r.x & 0xFFFF) * FOUT + lane]);
                    atomicAdd(&out[(size_t)node * FOUT + lane],
                              v * __int_as_float(r.y));
                }
            }
        }
    }
}

extern "C" void kernel_launch(void* const* d_in, const int* in_sizes, int n_in,
                              void* d_out, int out_size, void* d_ws, size_t ws_size,
                              hipStream_t stream) {
    const float* x    = (const float*)d_in[0];
    const float* t    = (const float*)d_in[1];
    const int*   src  = (const int*)d_in[2];
    const int*   dst  = (const int*)d_in[3];
    const float* ev   = (const float*)d_in[4];
    const float* W    = (const float*)d_in[5];
    const float* bias = (const float*)d_in[6];
    float* out = (float*)d_out;

    const int N = in_sizes[1];   // 50000
    const int E = in_sizes[2];   // 800000

    char*   ws      = (char*)d_ws;
    ushort* support = (ushort*)ws;
    int*    cur     = (int*)(ws + OFF_CUR);
    int*    ovfc    = (int*)(ws + OFF_OVFC);
    int2*   tmp     = (int2*)(ws + OFF_TMP);
    int4*   ovf     = (int4*)(ws + OFF_OVF);

    const int GB   = (N + TILE_ROWS - 1) / TILE_ROWS;       // 196
    const int SBP  = (E + EPB - 1) / EPB;                   // 98
    const int NBUK = (N + NPB - 1) / NPB;                   // 1563

    // zero bucket cursors + overflow count (6.5 KB, graph-capturable)
    hipMemsetAsync(ws + OFF_CUR, 0, OFF_TMP - OFF_CUR, stream);

    // 1) fused independent branches (1024-thread blocks): gemm || scatter
    gemm_scatter_kernel<<<GB + SBP, 1024, 0, stream>>>(
        x, t, W, support, N, src, dst, ev, cur, tmp, ovfc, ovf,
        E, SBP, NBUK, GB);

    // 2) per-bucket direct-claim sort + 8-deep group-per-node walk -> out
    bucket_gather_kernel<<<NBUK, 256, 0, stream>>>(
        cur, tmp, support, bias, out, ovfc, ovf, E, N, NBUK);
}

// Round 15
// 116.839 us; speedup vs baseline: 1.1961x; 1.0092x over previous
//
#include <hip/hip_runtime.h>
#include <hip/hip_bf16.h>

#define FIN 128
#define FOUT 64
#define TILE_ROWS 256      // rows per gemm block = 16 waves x 16

#define EPB 8192           // edges per scatter chunk (98 blocks x 16 waves)
#define NPB 32             // nodes per scatter bucket (d >> 5)
#define NBUK_MAX 1600
#define CAP 768            // records per bucket region (mean 512, +11 sigma)
#define NCAP 48            // LDS record slots per node (mean 16, +8 sigma)
#define NPG 16             // nodes per gather block (half a bucket)

// Workspace layout (bytes), ws >= 268 MB:
//   [0, 6,400,000)         support : N*64 bf16
//   OFF_CUR   +6,400       cur     : NBUK int (bucket fill counters)
//   OFF_OVFC  +64          ovfc    : 1 int (overflow count)
//   OFF_TMP   +9,830,400   tmp     : NBUK_MAX*CAP int2 regions {src|dloc<<16, ev}
//   OFF_OVF   +12,800,000  ovf     : E int4 {recx, recy, bucket, pad}
#define OFF_CUR   6400000
#define OFF_OVFC  6406400
#define OFF_TMP   6406464
#define OFF_OVF   16236864

typedef short bf16x8 __attribute__((ext_vector_type(8)));
typedef float f32x4  __attribute__((ext_vector_type(4)));

__device__ inline ushort f32_to_bf16_rne(float f) {
    unsigned u = __float_as_uint(f);
    u += 0x7FFFu + ((u >> 16) & 1u);
    return (ushort)(u >> 16);
}
__device__ inline float bf16_to_f32(ushort h) {
    return __uint_as_float((unsigned)h << 16);
}

// ---------------------------------------------------------------------------
// Fused, independent branches, 1024-thread blocks (no fences) -- R14 k1,
// byte-identical:
//   blocks [0,GB):       MFMA gemm, 256-row tiles (16 waves x 16 rows)
//   blocks [GB,GB+SBP):  scatter chunk EPB=8192, 16 waves/block, with
//                        register-held records (load once, no re-reads).
// rec = {src | (d&31)<<16, ev_bits}   (src < 65536: N = 50000 ok)
// NOTE (R8): never use fp LDS atomics on gfx950 (308us RMW stall).
// NOTE (R9/R11): keep scatter waves ~1500+; few-wave configs tail out.
// ---------------------------------------------------------------------------
union __align__(16) K1Sh {
    ushort wt[FOUT * FIN];                            // 16 KB (gemm)
    struct { int h[NBUK_MAX]; int c[NBUK_MAX]; } sc;  // 12.8 KB (scatter)
};

__global__ __launch_bounds__(1024) void gemm_scatter_kernel(
    const float* __restrict__ x, const float* __restrict__ t,
    const float* __restrict__ W, ushort* __restrict__ support, int N,
    const int* __restrict__ src, const int* __restrict__ dst,
    const float* __restrict__ ev, int* __restrict__ cur,
    int2* __restrict__ tmp, int* __restrict__ ovfc, int4* __restrict__ ovf,
    int E, int SBP, int NBUK, int GB)
{
    __shared__ K1Sh sh;
    const int tid = threadIdx.x;

    if (blockIdx.x >= (unsigned)GB) {
        // ---- scatter branch: 16 waves, EPB 8192, 8 edges/thread in regs ----
        const int chunk = blockIdx.x - GB;
        const int e0    = chunk * EPB;

        for (int i = tid; i < NBUK; i += 1024) sh.sc.h[i] = 0;
        __syncthreads();

        // pass 1: load once -> registers; count buckets
        int2 rec[8];
        int  bk[8];
        #pragma unroll
        for (int u = 0; u < 8; ++u) {
            int e = e0 + tid + u * 1024;
            bk[u] = -1;
            if (e < E) {
                int d = dst[e];
                bk[u]  = d >> 5;
                rec[u] = make_int2(src[e] | ((d & (NPB - 1)) << 16),
                                   __float_as_int(ev[e]));
                atomicAdd(&sh.sc.h[bk[u]], 1);
            }
        }
        __syncthreads();

        // pass 2: reserve contiguous slices of bucket regions
        for (int j = tid; j < NBUK; j += 1024) {
            int hj = sh.sc.h[j];
            if (hj) sh.sc.c[j] = atomicAdd(&cur[j], hj);
        }
        __syncthreads();

        // pass 3: claim LDS cursor, store register-held record
        #pragma unroll
        for (int u = 0; u < 8; ++u) {
            if (bk[u] >= 0) {
                int s = atomicAdd(&sh.sc.c[bk[u]], 1);
                if (s < CAP) {
                    tmp[(size_t)bk[u] * CAP + s] = rec[u];
                } else {                 // never at this size; kept correct
                    int o = atomicAdd(ovfc, 1);
                    if (o < E) ovf[o] = make_int4(rec[u].x, rec[u].y, bk[u], 0);
                }
            }
        }
        return;
    }

    // ---- MFMA gemm branch: 256-row tile, 16 waves x 16 rows ----
    const int gb   = blockIdx.x;
    const int lane = tid & 63;
    const int w    = tid >> 6;          // wave 0..15
    const int ln   = lane & 15;
    const int q    = lane >> 4;         // quad 0..3
    const int rowb = gb * TILE_ROWS + w * 16;
    const int arow = rowb + ln;

    // Stage W -> LDS bf16, transposed WT[n][k]; 16B slot XOR-swizzled by n&7.
    #pragma unroll
    for (int it = 0; it < 2; ++it) {
        int eidx = (tid + it * 1024) * 4;       // element index; 4 consecutive n
        float4 wv = *(const float4*)&W[eidx];
        int k  = eidx >> 6;                     // 0..127
        int n0 = eidx & 63;                     // 0,4,..,60
        sh.wt[(n0 + 0) * FIN + (k ^ (((n0 + 0) & 7) << 3))] = f32_to_bf16_rne(wv.x);
        sh.wt[(n0 + 1) * FIN + (k ^ (((n0 + 1) & 7) << 3))] = f32_to_bf16_rne(wv.y);
        sh.wt[(n0 + 2) * FIN + (k ^ (((n0 + 2) & 7) << 3))] = f32_to_bf16_rne(wv.z);
        sh.wt[(n0 + 3) * FIN + (k ^ (((n0 + 3) & 7) << 3))] = f32_to_bf16_rne(wv.w);
    }
    __syncthreads();

    f32x4 acc[4];
    #pragma unroll
    for (int nt = 0; nt < 4; ++nt)
        #pragma unroll
        for (int r = 0; r < 4; ++r) acc[nt][r] = 0.f;

    const bool aok = (arow < N);
    const float* xrow = &x[(size_t)arow * FIN];

    #pragma unroll
    for (int kc = 0; kc < 4; ++kc) {
        float xs[8];
        #pragma unroll
        for (int j = 0; j < 8; ++j) xs[j] = 0.f;
        if (aok) {
            float4 x0 = *(const float4*)&xrow[kc * 32 + q * 8];
            float4 x1 = *(const float4*)&xrow[kc * 32 + q * 8 + 4];
            xs[0] = x0.x; xs[1] = x0.y; xs[2] = x0.z; xs[3] = x0.w;
            xs[4] = x1.x; xs[5] = x1.y; xs[6] = x1.z; xs[7] = x1.w;
        }
        bf16x8 a;
        #pragma unroll
        for (int j = 0; j < 8; ++j) a[j] = (short)f32_to_bf16_rne(xs[j]);

        const int k0 = kc * 32 + q * 8;
        #pragma unroll
        for (int nt = 0; nt < 4; ++nt) {
            bf16x8 b = *(const bf16x8*)
                &sh.wt[(nt * 16 + ln) * FIN + (k0 ^ ((ln & 7) << 3))];
            acc[nt] = __builtin_amdgcn_mfma_f32_16x16x32_bf16(a, b, acc[nt], 0, 0, 0);
        }
    }

    // epilogue: D[m=q*4+reg][n=ln]; scale by t[row]; store bf16
    #pragma unroll
    for (int reg = 0; reg < 4; ++reg) {
        int r = rowb + q * 4 + reg;
        if (r < N) {
            float tv = t[r];
            #pragma unroll
            for (int nt = 0; nt < 4; ++nt)
                support[(size_t)r * FOUT + nt * 16 + ln] =
                    f32_to_bf16_rne(acc[nt][reg] * tv);
        }
    }
}

// ---------------------------------------------------------------------------
// bucket_gather v5: TWO blocks per bucket region (split on dloc bit 4) ->
// 3126 blocks, 16 nodes each. LDS halves to ~6.2KB -> 8 blocks/CU (32/32
// waves, was 24/32). Each 16-lane group owns exactly ONE node (no sub loop;
// wave time = max of 4 node degrees). Single-pass direct-claim sort with
// filter; 8-deep MLP walk; full 128B support row per record (16 x uint2);
// float4 store (+bias). Cost: each region read twice (+12.5MB seq).
// Per-node overflow (P~1e-13): serial recompute. Region overflow: tail.
// ---------------------------------------------------------------------------
__global__ __launch_bounds__(256) void bucket_gather_kernel(
    const int* __restrict__ curg, const int2* __restrict__ tmp,
    const ushort* __restrict__ support, const float* __restrict__ bias,
    float* __restrict__ out, const int* __restrict__ ovfc,
    const int4* __restrict__ ovf, int E, int N, int NBUK)
{
    __shared__ int2 sorted[NPG * NCAP];   // 6.1 KB
    __shared__ int  cnt[NPG];
    __shared__ int  novs;

    const int tid   = threadIdx.x;
    const int w     = tid >> 6;
    const int lane  = tid & 63;
    const int B     = blockIdx.x >> 1;    // bucket region
    const int half  = blockIdx.x & 1;     // which 16-node half
    const int node0 = B * NPB + half * NPG;

    const int base   = B * CAP;
    const int tot    = curg[B];
    const int placed = (tot < CAP) ? tot : CAP;

    if (tid < NPG) cnt[tid] = 0;
    __syncthreads();

    // single pass: global read -> filter half -> claim slot -> direct place
    for (int i = tid; i < placed; i += 256) {
        int2 r  = tmp[base + i];
        int nl5 = (r.x >> 16) & (NPB - 1);
        if ((nl5 >> 4) == half) {
            int nl = nl5 & (NPG - 1);
            int s  = atomicAdd(&cnt[nl], 1);
            if (s < NCAP) sorted[nl * NCAP + s] = r;
        }
    }
    __syncthreads();

    // ---- walk: group g (tid>>4) owns node g; fl = tid&15 ----
    const int fl = tid & 15;            // feature block 0..15 (4 feats each)
    const int g  = tid >> 4;            // group == node-local index 0..15
    const float4 bv4 = *(const float4*)&bias[fl * 4];

    {
        const int nl = g;
        const int c  = cnt[nl];
        if (c <= NCAP) {                // group-uniform; serial path below
            const int rb = nl * NCAP;
            const int re = rb + c;

            float a0 = 0.f, a1 = 0.f, a2 = 0.f, a3 = 0.f;
            int i = rb;
            for (; i + 8 <= re; i += 8) {          // 8 records in flight
                int2 rr[8];
                #pragma unroll
                for (int u = 0; u < 8; ++u) rr[u] = sorted[i + u];
                uint2 uu[8];
                #pragma unroll
                for (int u = 0; u < 8; ++u)
                    uu[u] = *(const uint2*)
                        &support[(size_t)(rr[u].x & 0xFFFF) * FOUT + fl * 4];
                #pragma unroll
                for (int u = 0; u < 8; ++u) {
                    float wg = __int_as_float(rr[u].y);
                    a0 += bf16_to_f32((ushort)(uu[u].x & 0xFFFFu)) * wg;
                    a1 += bf16_to_f32((ushort)(uu[u].x >> 16)) * wg;
                    a2 += bf16_to_f32((ushort)(uu[u].y & 0xFFFFu)) * wg;
                    a3 += bf16_to_f32((ushort)(uu[u].y >> 16)) * wg;
                }
            }
            for (; i + 4 <= re; i += 4) {          // 4 records in flight
                int2 r0 = sorted[i],     r1 = sorted[i + 1];
                int2 r2 = sorted[i + 2], r3 = sorted[i + 3];
                uint2 u0 = *(const uint2*)&support[(size_t)(r0.x & 0xFFFF) * FOUT + fl * 4];
                uint2 u1 = *(const uint2*)&support[(size_t)(r1.x & 0xFFFF) * FOUT + fl * 4];
                uint2 u2 = *(const uint2*)&support[(size_t)(r2.x & 0xFFFF) * FOUT + fl * 4];
                uint2 u3 = *(const uint2*)&support[(size_t)(r3.x & 0xFFFF) * FOUT + fl * 4];
                float w0 = __int_as_float(r0.y), w1 = __int_as_float(r1.y);
                float w2 = __int_as_float(r2.y), w3 = __int_as_float(r3.y);
                a0 += bf16_to_f32((ushort)(u0.x & 0xFFFFu)) * w0;
                a1 += bf16_to_f32((ushort)(u0.x >> 16)) * w0;
                a2 += bf16_to_f32((ushort)(u0.y & 0xFFFFu)) * w0;
                a3 += bf16_to_f32((ushort)(u0.y >> 16)) * w0;
                a0 += bf16_to_f32((ushort)(u1.x & 0xFFFFu)) * w1;
                a1 += bf16_to_f32((ushort)(u1.x >> 16)) * w1;
                a2 += bf16_to_f32((ushort)(u1.y & 0xFFFFu)) * w1;
                a3 += bf16_to_f32((ushort)(u1.y >> 16)) * w1;
                a0 += bf16_to_f32((ushort)(u2.x & 0xFFFFu)) * w2;
                a1 += bf16_to_f32((ushort)(u2.x >> 16)) * w2;
                a2 += bf16_to_f32((ushort)(u2.y & 0xFFFFu)) * w2;
                a3 += bf16_to_f32((ushort)(u2.y >> 16)) * w2;
                a0 += bf16_to_f32((ushort)(u3.x & 0xFFFFu)) * w3;
                a1 += bf16_to_f32((ushort)(u3.x >> 16)) * w3;
                a2 += bf16_to_f32((ushort)(u3.y & 0xFFFFu)) * w3;
                a3 += bf16_to_f32((ushort)(u3.y >> 16)) * w3;
            }
            for (; i < re; ++i) {
                int2 r = sorted[i];
                uint2 u = *(const uint2*)&support[(size_t)(r.x & 0xFFFF) * FOUT + fl * 4];
                float wg = __int_as_float(r.y);
                a0 += bf16_to_f32((ushort)(u.x & 0xFFFFu)) * wg;
                a1 += bf16_to_f32((ushort)(u.x >> 16)) * wg;
                a2 += bf16_to_f32((ushort)(u.y & 0xFFFFu)) * wg;
                a3 += bf16_to_f32((ushort)(u.y >> 16)) * wg;
            }
            const int node = node0 + nl;
            if (node < N) {
                float4 o;
                o.x = a0 + bv4.x; o.y = a1 + bv4.y;
                o.z = a2 + bv4.z; o.w = a3 + bv4.w;
                *(float4*)&out[(size_t)node * FOUT + fl * 4] = o;
            }
        }
    }
    __syncthreads();

    // per-node overflow recompute: never taken (P ~ 5e-9 total); block-uniform
    for (int nl = 0; nl < NPG; ++nl) {
        if (cnt[nl] > NCAP) {
            const int node = node0 + nl;
            const int nl5  = half * NPG + nl;
            if (tid < 16 && node < N) {
                float a0 = 0.f, a1 = 0.f, a2 = 0.f, a3 = 0.f;
                for (int i = 0; i < placed; ++i) {
                    int2 r = tmp[base + i];
                    if (((r.x >> 16) & (NPB - 1)) == nl5) {
                        uint2 u = *(const uint2*)
                            &support[(size_t)(r.x & 0xFFFF) * FOUT + tid * 4];
                        float wg = __int_as_float(r.y);
                        a0 += bf16_to_f32((ushort)(u.x & 0xFFFFu)) * wg;
                        a1 += bf16_to_f32((ushort)(u.x >> 16)) * wg;
                        a2 += bf16_to_f32((ushort)(u.y & 0xFFFFu)) * wg;
                        a3 += bf16_to_f32((ushort)(u.y >> 16)) * wg;
                    }
                }
                float4 o;
                o.x = a0 + bias[tid * 4 + 0]; o.y = a1 + bias[tid * 4 + 1];
                o.z = a2 + bias[tid * 4 + 2]; o.w = a3 + bias[tid * 4 + 3];
                *(float4*)&out[(size_t)node * FOUT + tid * 4] = o;
            }
        }
    }

    // region-overflow tail: never taken at this size; kept for correctness.
    __syncthreads();
    if (tid == 0) novs = *ovfc;
    __syncthreads();
    int nov = novs;
    if (nov > 0) {
        if (nov > E) nov = E;
        __threadfence();
        for (int k = w; k < nov; k += 4) {
            int4 r = ovf[k];
            int nl5 = (r.x >> 16) & (NPB - 1);
            if (r.z == B && (nl5 >> 4) == half) {
                int node = node0 + (nl5 & (NPG - 1));
                if (node < N) {
                    float v = bf16_to_f32(
                        support[(size_t)(r.x & 0xFFFF) * FOUT + lane]);
                    atomicAdd(&out[(size_t)node * FOUT + lane],
                              v * __int_as_float(r.y));
                }
            }
        }
    }
}

extern "C" void kernel_launch(void* const* d_in, const int* in_sizes, int n_in,
                              void* d_out, int out_size, void* d_ws, size_t ws_size,
                              hipStream_t stream) {
    const float* x    = (const float*)d_in[0];
    const float* t    = (const float*)d_in[1];
    const int*   src  = (const int*)d_in[2];
    const int*   dst  = (const int*)d_in[3];
    const float* ev   = (const float*)d_in[4];
    const float* W    = (const float*)d_in[5];
    const float* bias = (const float*)d_in[6];
    float* out = (float*)d_out;

    const int N = in_sizes[1];   // 50000
    const int E = in_sizes[2];   // 800000

    char*   ws      = (char*)d_ws;
    ushort* support = (ushort*)ws;
    int*    cur     = (int*)(ws + OFF_CUR);
    int*    ovfc    = (int*)(ws + OFF_OVFC);
    int2*   tmp     = (int2*)(ws + OFF_TMP);
    int4*   ovf     = (int4*)(ws + OFF_OVF);

    const int GB   = (N + TILE_ROWS - 1) / TILE_ROWS;       // 196
    const int SBP  = (E + EPB - 1) / EPB;                   // 98
    const int NBUK = (N + NPB - 1) / NPB;                   // 1563

    // zero bucket cursors + overflow count (6.5 KB, graph-capturable)
    hipMemsetAsync(ws + OFF_CUR, 0, OFF_TMP - OFF_CUR, stream);

    // 1) fused independent branches (1024-thread blocks): gemm || scatter
    gemm_scatter_kernel<<<GB + SBP, 1024, 0, stream>>>(
        x, t, W, support, N, src, dst, ev, cur, tmp, ovfc, ovf,
        E, SBP, NBUK, GB);

    // 2) half-bucket gather blocks (2x TLP) + 1-node-per-group walk -> out
    bucket_gather_kernel<<<2 * NBUK, 256, 0, stream>>>(
        cur, tmp, support, bias, out, ovfc, ovf, E, N, NBUK);
}

// Round 16
// 113.699 us; speedup vs baseline: 1.2292x; 1.0276x over previous
//
#include <hip/hip_runtime.h>
#include <hip/hip_bf16.h>

#define FIN 128
#define FOUT 64
#define TILE_ROWS 256      // rows per gemm block = 16 waves x 16

#define EPB 4096           // edges per scatter chunk (196 blocks x 16 waves)
#define NPB 32             // nodes per scatter bucket (d >> 5)
#define NBUK_MAX 1600
#define CAP 768            // records per bucket region (mean 512, +11 sigma)
#define NCAP 48            // LDS record slots per node (mean 16, +8 sigma)
#define NPG 16             // nodes per gather block (half a bucket)

// Workspace layout (bytes), ws >= 268 MB:
//   [0, 6,400,000)         support : N*64 bf16
//   OFF_CUR   +6,400       cur     : NBUK int (bucket fill counters)
//   OFF_OVFC  +64          ovfc    : 1 int (overflow count)
//   OFF_TMP   +9,830,400   tmp     : NBUK_MAX*CAP int2 regions {src|dloc<<16, ev}
//   OFF_OVF   +12,800,000  ovf     : E int4 {recx, recy, bucket, pad}
#define OFF_CUR   6400000
#define OFF_OVFC  6406400
#define OFF_TMP   6406464
#define OFF_OVF   16236864

typedef short bf16x8 __attribute__((ext_vector_type(8)));
typedef float f32x4  __attribute__((ext_vector_type(4)));

__device__ inline ushort f32_to_bf16_rne(float f) {
    unsigned u = __float_as_uint(f);
    u += 0x7FFFu + ((u >> 16) & 1u);
    return (ushort)(u >> 16);
}
__device__ inline float bf16_to_f32(ushort h) {
    return __uint_as_float((unsigned)h << 16);
}

// ---------------------------------------------------------------------------
// Fused, independent branches, 1024-thread blocks (no fences):
//   blocks [0,GB):       MFMA gemm, 256-row tiles (16 waves x 16 rows)
//   blocks [GB,GB+SBP):  scatter chunk EPB=4096, 16 waves/block, with
//                        register-held records (load once, no re-reads).
// R16: SBP 98 -> 196 (EPB 8192 -> 4096). k1's branches run on disjoint CU
// sets; 98 scatter blocks used <=38% of CUs after the short GEMM drained.
// 196+196 = 392 blocks = 1.53/CU, fully co-resident; scatter waves 2x.
// Cost: run length 5.2 -> 2.6 records (tmp write ~21 -> ~28MB, known from
// R10/R11 A/B). rec = {src | (d&31)<<16, ev_bits}  (src < 65536: N=50000 ok)
// NOTE (R8): never use fp LDS atomics on gfx950 (308us RMW stall).
// NOTE (R9/R11): keep scatter waves ~1500+; few-wave configs tail out.
// ---------------------------------------------------------------------------
union __align__(16) K1Sh {
    ushort wt[FOUT * FIN];                            // 16 KB (gemm)
    struct { int h[NBUK_MAX]; int c[NBUK_MAX]; } sc;  // 12.8 KB (scatter)
};

__global__ __launch_bounds__(1024) void gemm_scatter_kernel(
    const float* __restrict__ x, const float* __restrict__ t,
    const float* __restrict__ W, ushort* __restrict__ support, int N,
    const int* __restrict__ src, const int* __restrict__ dst,
    const float* __restrict__ ev, int* __restrict__ cur,
    int2* __restrict__ tmp, int* __restrict__ ovfc, int4* __restrict__ ovf,
    int E, int SBP, int NBUK, int GB)
{
    __shared__ K1Sh sh;
    const int tid = threadIdx.x;

    if (blockIdx.x >= (unsigned)GB) {
        // ---- scatter branch: 16 waves, EPB 4096, 4 edges/thread in regs ----
        const int chunk = blockIdx.x - GB;
        const int e0    = chunk * EPB;

        for (int i = tid; i < NBUK; i += 1024) sh.sc.h[i] = 0;
        __syncthreads();

        // pass 1: load once -> registers; count buckets
        int2 rec[4];
        int  bk[4];
        #pragma unroll
        for (int u = 0; u < 4; ++u) {
            int e = e0 + tid + u * 1024;
            bk[u] = -1;
            if (e < E) {
                int d = dst[e];
                bk[u]  = d >> 5;
                rec[u] = make_int2(src[e] | ((d & (NPB - 1)) << 16),
                                   __float_as_int(ev[e]));
                atomicAdd(&sh.sc.h[bk[u]], 1);
            }
        }
        __syncthreads();

        // pass 2: reserve contiguous slices of bucket regions
        for (int j = tid; j < NBUK; j += 1024) {
            int hj = sh.sc.h[j];
            if (hj) sh.sc.c[j] = atomicAdd(&cur[j], hj);
        }
        __syncthreads();

        // pass 3: claim LDS cursor, store register-held record
        #pragma unroll
        for (int u = 0; u < 4; ++u) {
            if (bk[u] >= 0) {
                int s = atomicAdd(&sh.sc.c[bk[u]], 1);
                if (s < CAP) {
                    tmp[(size_t)bk[u] * CAP + s] = rec[u];
                } else {                 // never at this size; kept correct
                    int o = atomicAdd(ovfc, 1);
                    if (o < E) ovf[o] = make_int4(rec[u].x, rec[u].y, bk[u], 0);
                }
            }
        }
        return;
    }

    // ---- MFMA gemm branch: 256-row tile, 16 waves x 16 rows ----
    const int gb   = blockIdx.x;
    const int lane = tid & 63;
    const int w    = tid >> 6;          // wave 0..15
    const int ln   = lane & 15;
    const int q    = lane >> 4;         // quad 0..3
    const int rowb = gb * TILE_ROWS + w * 16;
    const int arow = rowb + ln;

    // Stage W -> LDS bf16, transposed WT[n][k]; 16B slot XOR-swizzled by n&7.
    #pragma unroll
    for (int it = 0; it < 2; ++it) {
        int eidx = (tid + it * 1024) * 4;       // element index; 4 consecutive n
        float4 wv = *(const float4*)&W[eidx];
        int k  = eidx >> 6;                     // 0..127
        int n0 = eidx & 63;                     // 0,4,..,60
        sh.wt[(n0 + 0) * FIN + (k ^ (((n0 + 0) & 7) << 3))] = f32_to_bf16_rne(wv.x);
        sh.wt[(n0 + 1) * FIN + (k ^ (((n0 + 1) & 7) << 3))] = f32_to_bf16_rne(wv.y);
        sh.wt[(n0 + 2) * FIN + (k ^ (((n0 + 2) & 7) << 3))] = f32_to_bf16_rne(wv.z);
        sh.wt[(n0 + 3) * FIN + (k ^ (((n0 + 3) & 7) << 3))] = f32_to_bf16_rne(wv.w);
    }
    __syncthreads();

    f32x4 acc[4];
    #pragma unroll
    for (int nt = 0; nt < 4; ++nt)
        #pragma unroll
        for (int r = 0; r < 4; ++r) acc[nt][r] = 0.f;

    const bool aok = (arow < N);
    const float* xrow = &x[(size_t)arow * FIN];

    #pragma unroll
    for (int kc = 0; kc < 4; ++kc) {
        float xs[8];
        #pragma unroll
        for (int j = 0; j < 8; ++j) xs[j] = 0.f;
        if (aok) {
            float4 x0 = *(const float4*)&xrow[kc * 32 + q * 8];
            float4 x1 = *(const float4*)&xrow[kc * 32 + q * 8 + 4];
            xs[0] = x0.x; xs[1] = x0.y; xs[2] = x0.z; xs[3] = x0.w;
            xs[4] = x1.x; xs[5] = x1.y; xs[6] = x1.z; xs[7] = x1.w;
        }
        bf16x8 a;
        #pragma unroll
        for (int j = 0; j < 8; ++j) a[j] = (short)f32_to_bf16_rne(xs[j]);

        const int k0 = kc * 32 + q * 8;
        #pragma unroll
        for (int nt = 0; nt < 4; ++nt) {
            bf16x8 b = *(const bf16x8*)
                &sh.wt[(nt * 16 + ln) * FIN + (k0 ^ ((ln & 7) << 3))];
            acc[nt] = __builtin_amdgcn_mfma_f32_16x16x32_bf16(a, b, acc[nt], 0, 0, 0);
        }
    }

    // epilogue: D[m=q*4+reg][n=ln]; scale by t[row]; store bf16
    #pragma unroll
    for (int reg = 0; reg < 4; ++reg) {
        int r = rowb + q * 4 + reg;
        if (r < N) {
            float tv = t[r];
            #pragma unroll
            for (int nt = 0; nt < 4; ++nt)
                support[(size_t)r * FOUT + nt * 16 + ln] =
                    f32_to_bf16_rne(acc[nt][reg] * tv);
        }
    }
}

// ---------------------------------------------------------------------------
// bucket_gather v5 (R15, unchanged): TWO blocks per bucket region (split on
// dloc bit 4) -> 3126 blocks, 16 nodes each, ~6.2KB LDS (8 blocks/CU).
// Each 16-lane group owns exactly ONE node. Single-pass direct-claim sort
// with filter; 8-deep MLP walk; full 128B support row per record; float4
// store (+bias). Per-node overflow (P~1e-13): serial recompute. Region
// overflow: atomic tail.
// ---------------------------------------------------------------------------
__global__ __launch_bounds__(256) void bucket_gather_kernel(
    const int* __restrict__ curg, const int2* __restrict__ tmp,
    const ushort* __restrict__ support, const float* __restrict__ bias,
    float* __restrict__ out, const int* __restrict__ ovfc,
    const int4* __restrict__ ovf, int E, int N, int NBUK)
{
    __shared__ int2 sorted[NPG * NCAP];   // 6.1 KB
    __shared__ int  cnt[NPG];
    __shared__ int  novs;

    const int tid   = threadIdx.x;
    const int w     = tid >> 6;
    const int lane  = tid & 63;
    const int B     = blockIdx.x >> 1;    // bucket region
    const int half  = blockIdx.x & 1;     // which 16-node half
    const int node0 = B * NPB + half * NPG;

    const int base   = B * CAP;
    const int tot    = curg[B];
    const int placed = (tot < CAP) ? tot : CAP;

    if (tid < NPG) cnt[tid] = 0;
    __syncthreads();

    // single pass: global read -> filter half -> claim slot -> direct place
    for (int i = tid; i < placed; i += 256) {
        int2 r  = tmp[base + i];
        int nl5 = (r.x >> 16) & (NPB - 1);
        if ((nl5 >> 4) == half) {
            int nl = nl5 & (NPG - 1);
            int s  = atomicAdd(&cnt[nl], 1);
            if (s < NCAP) sorted[nl * NCAP + s] = r;
        }
    }
    __syncthreads();

    // ---- walk: group g (tid>>4) owns node g; fl = tid&15 ----
    const int fl = tid & 15;            // feature block 0..15 (4 feats each)
    const int g  = tid >> 4;            // group == node-local index 0..15
    const float4 bv4 = *(const float4*)&bias[fl * 4];

    {
        const int nl = g;
        const int c  = cnt[nl];
        if (c <= NCAP) {                // group-uniform; serial path below
            const int rb = nl * NCAP;
            const int re = rb + c;

            float a0 = 0.f, a1 = 0.f, a2 = 0.f, a3 = 0.f;
            int i = rb;
            for (; i + 8 <= re; i += 8) {          // 8 records in flight
                int2 rr[8];
                #pragma unroll
                for (int u = 0; u < 8; ++u) rr[u] = sorted[i + u];
                uint2 uu[8];
                #pragma unroll
                for (int u = 0; u < 8; ++u)
                    uu[u] = *(const uint2*)
                        &support[(size_t)(rr[u].x & 0xFFFF) * FOUT + fl * 4];
                #pragma unroll
                for (int u = 0; u < 8; ++u) {
                    float wg = __int_as_float(rr[u].y);
                    a0 += bf16_to_f32((ushort)(uu[u].x & 0xFFFFu)) * wg;
                    a1 += bf16_to_f32((ushort)(uu[u].x >> 16)) * wg;
                    a2 += bf16_to_f32((ushort)(uu[u].y & 0xFFFFu)) * wg;
                    a3 += bf16_to_f32((ushort)(uu[u].y >> 16)) * wg;
                }
            }
            for (; i + 4 <= re; i += 4) {          // 4 records in flight
                int2 r0 = sorted[i],     r1 = sorted[i + 1];
                int2 r2 = sorted[i + 2], r3 = sorted[i + 3];
                uint2 u0 = *(const uint2*)&support[(size_t)(r0.x & 0xFFFF) * FOUT + fl * 4];
                uint2 u1 = *(const uint2*)&support[(size_t)(r1.x & 0xFFFF) * FOUT + fl * 4];
                uint2 u2 = *(const uint2*)&support[(size_t)(r2.x & 0xFFFF) * FOUT + fl * 4];
                uint2 u3 = *(const uint2*)&support[(size_t)(r3.x & 0xFFFF) * FOUT + fl * 4];
                float w0 = __int_as_float(r0.y), w1 = __int_as_float(r1.y);
                float w2 = __int_as_float(r2.y), w3 = __int_as_float(r3.y);
                a0 += bf16_to_f32((ushort)(u0.x & 0xFFFFu)) * w0;
                a1 += bf16_to_f32((ushort)(u0.x >> 16)) * w0;
                a2 += bf16_to_f32((ushort)(u0.y & 0xFFFFu)) * w0;
                a3 += bf16_to_f32((ushort)(u0.y >> 16)) * w0;
                a0 += bf16_to_f32((ushort)(u1.x & 0xFFFFu)) * w1;
                a1 += bf16_to_f32((ushort)(u1.x >> 16)) * w1;
                a2 += bf16_to_f32((ushort)(u1.y & 0xFFFFu)) * w1;
                a3 += bf16_to_f32((ushort)(u1.y >> 16)) * w1;
                a0 += bf16_to_f32((ushort)(u2.x & 0xFFFFu)) * w2;
                a1 += bf16_to_f32((ushort)(u2.x >> 16)) * w2;
                a2 += bf16_to_f32((ushort)(u2.y & 0xFFFFu)) * w2;
                a3 += bf16_to_f32((ushort)(u2.y >> 16)) * w2;
                a0 += bf16_to_f32((ushort)(u3.x & 0xFFFFu)) * w3;
                a1 += bf16_to_f32((ushort)(u3.x >> 16)) * w3;
                a2 += bf16_to_f32((ushort)(u3.y & 0xFFFFu)) * w3;
                a3 += bf16_to_f32((ushort)(u3.y >> 16)) * w3;
            }
            for (; i < re; ++i) {
                int2 r = sorted[i];
                uint2 u = *(const uint2*)&support[(size_t)(r.x & 0xFFFF) * FOUT + fl * 4];
                float wg = __int_as_float(r.y);
                a0 += bf16_to_f32((ushort)(u.x & 0xFFFFu)) * wg;
                a1 += bf16_to_f32((ushort)(u.x >> 16)) * wg;
                a2 += bf16_to_f32((ushort)(u.y & 0xFFFFu)) * wg;
                a3 += bf16_to_f32((ushort)(u.y >> 16)) * wg;
            }
            const int node = node0 + nl;
            if (node < N) {
                float4 o;
                o.x = a0 + bv4.x; o.y = a1 + bv4.y;
                o.z = a2 + bv4.z; o.w = a3 + bv4.w;
                *(float4*)&out[(size_t)node * FOUT + fl * 4] = o;
            }
        }
    }
    __syncthreads();

    // per-node overflow recompute: never taken (P ~ 5e-9 total); block-uniform
    for (int nl = 0; nl < NPG; ++nl) {
        if (cnt[nl] > NCAP) {
            const int node = node0 + nl;
            const int nl5  = half * NPG + nl;
            if (tid < 16 && node < N) {
                float a0 = 0.f, a1 = 0.f, a2 = 0.f, a3 = 0.f;
                for (int i = 0; i < placed; ++i) {
                    int2 r = tmp[base + i];
                    if (((r.x >> 16) & (NPB - 1)) == nl5) {
                        uint2 u = *(const uint2*)
                            &support[(size_t)(r.x & 0xFFFF) * FOUT + tid * 4];
                        float wg = __int_as_float(r.y);
                        a0 += bf16_to_f32((ushort)(u.x & 0xFFFFu)) * wg;
                        a1 += bf16_to_f32((ushort)(u.x >> 16)) * wg;
                        a2 += bf16_to_f32((ushort)(u.y & 0xFFFFu)) * wg;
                        a3 += bf16_to_f32((ushort)(u.y >> 16)) * wg;
                    }
                }
                float4 o;
                o.x = a0 + bias[tid * 4 + 0]; o.y = a1 + bias[tid * 4 + 1];
                o.z = a2 + bias[tid * 4 + 2]; o.w = a3 + bias[tid * 4 + 3];
                *(float4*)&out[(size_t)node * FOUT + tid * 4] = o;
            }
        }
    }

    // region-overflow tail: never taken at this size; kept for correctness.
    __syncthreads();
    if (tid == 0) novs = *ovfc;
    __syncthreads();
    int nov = novs;
    if (nov > 0) {
        if (nov > E) nov = E;
        __threadfence();
        for (int k = w; k < nov; k += 4) {
            int4 r = ovf[k];
            int nl5 = (r.x >> 16) & (NPB - 1);
            if (r.z == B && (nl5 >> 4) == half) {
                int node = node0 + (nl5 & (NPG - 1));
                if (node < N) {
                    float v = bf16_to_f32(
                        support[(size_t)(r.x & 0xFFFF) * FOUT + lane]);
                    atomicAdd(&out[(size_t)node * FOUT + lane],
                              v * __int_as_float(r.y));
                }
            }
        }
    }
}

extern "C" void kernel_launch(void* const* d_in, const int* in_sizes, int n_in,
                              void* d_out, int out_size, void* d_ws, size_t ws_size,
                              hipStream_t stream) {
    const float* x    = (const float*)d_in[0];
    const float* t    = (const float*)d_in[1];
    const int*   src  = (const int*)d_in[2];
    const int*   dst  = (const int*)d_in[3];
    const float* ev   = (const float*)d_in[4];
    const float* W    = (const float*)d_in[5];
    const float* bias = (const float*)d_in[6];
    float* out = (float*)d_out;

    const int N = in_sizes[1];   // 50000
    const int E = in_sizes[2];   // 800000

    char*   ws      = (char*)d_ws;
    ushort* support = (ushort*)ws;
    int*    cur     = (int*)(ws + OFF_CUR);
    int*    ovfc    = (int*)(ws + OFF_OVFC);
    int2*   tmp     = (int2*)(ws + OFF_TMP);
    int4*   ovf     = (int4*)(ws + OFF_OVF);

    const int GB   = (N + TILE_ROWS - 1) / TILE_ROWS;       // 196
    const int SBP  = (E + EPB - 1) / EPB;                   // 196
    const int NBUK = (N + NPB - 1) / NPB;                   // 1563

    // zero bucket cursors + overflow count (6.5 KB, graph-capturable)
    hipMemsetAsync(ws + OFF_CUR, 0, OFF_TMP - OFF_CUR, stream);

    // 1) fused independent branches (1024-thread blocks): gemm || scatter
    gemm_scatter_kernel<<<GB + SBP, 1024, 0, stream>>>(
        x, t, W, support, N, src, dst, ev, cur, tmp, ovfc, ovf,
        E, SBP, NBUK, GB);

    // 2) half-bucket gather blocks + 1-node-per-group walk -> out
    bucket_gather_kernel<<<2 * NBUK, 256, 0, stream>>>(
        cur, tmp, support, bias, out, ovfc, ovf, E, N, NBUK);
}